// Round 10
// baseline (488.069 us; speedup 1.0000x reference)
//
#include <hip/hip_runtime.h>
#include <hip/hip_bf16.h>
#include <math.h>

// ActorGNN R10: R9 + layer-3 gather table split into two 3.2MB feature planes
// (XCD-swizzled so each XCD L2 caches one plane) + non-temporal loads/stores
// for stream-once data to protect gather-table L2 residency.
// N=100000, E=3200000, G=64.

#define THREADS 256
#define TCSR 512
#define BSH 8
#define MAXNB 512
#define CH_E 2048
#define CPT 8
#define POOL_C 512

// ---- bf16 helpers ----
__device__ inline unsigned short f2bf(float f) {
    unsigned int u = __float_as_uint(f);
    return (unsigned short)((u + 0x7fffu + ((u >> 16) & 1u)) >> 16);  // RNE
}
__device__ inline unsigned int pk2bf(float a, float b) {
    return (unsigned int)f2bf(a) | ((unsigned int)f2bf(b) << 16);
}
__device__ inline float bflo(unsigned int u) { return __uint_as_float(u << 16); }
__device__ inline float bfhi(unsigned int u) { return __uint_as_float(u & 0xffff0000u); }
__device__ inline void unpk8(const uint4 u, float* f) {
    f[0] = bflo(u.x); f[1] = bfhi(u.x); f[2] = bflo(u.y); f[3] = bfhi(u.y);
    f[4] = bflo(u.z); f[5] = bfhi(u.z); f[6] = bflo(u.w); f[7] = bfhi(u.w);
}

// ---- non-temporal helpers ----
typedef float nt_f4 __attribute__((ext_vector_type(4)));
__device__ inline int ldnt(const int* p) { return __builtin_nontemporal_load(p); }
__device__ inline unsigned short ldnt_us(const unsigned short* p) { return __builtin_nontemporal_load(p); }
__device__ inline float ldnt_f(const float* p) { return __builtin_nontemporal_load(p); }
__device__ inline float4 ldnt_f4(const float* p) {
    nt_f4 v = __builtin_nontemporal_load((const nt_f4*)p);
    return make_float4(v.x, v.y, v.z, v.w);
}
__device__ inline void stnt_f4(float* p, float4 v) {
    nt_f4 w = {v.x, v.y, v.z, v.w};
    __builtin_nontemporal_store(w, (nt_f4*)p);
}

// ---- Atomic-free binning: pass A counts + records local position ----
__global__ void k_countA(const int* __restrict__ dst, unsigned short* __restrict__ lp16,
                         int* __restrict__ cnt_mat, int E, int NB, int NCH) {
    __shared__ int hist[MAXNB];
    int t = threadIdx.x, chunk = blockIdx.x;
    for (int h = t; h < NB; h += THREADS) hist[h] = 0;
    __syncthreads();
    int e0 = chunk * CH_E, e1 = min(E, e0 + CH_E);
    for (int e = e0 + t; e < e1; e += THREADS) {
        int h = ldnt(dst + e) >> BSH;
        int lp = atomicAdd(&hist[h], 1);
        lp16[e] = (unsigned short)lp;
    }
    __syncthreads();
    for (int h = t; h < NB; h += THREADS) cnt_mat[(size_t)h * NCH + chunk] = hist[h];
}

// K1: bucket totals
__global__ void k_sumK1(const int* __restrict__ cnt_mat, int* __restrict__ bucket_tot, int NCH) {
    __shared__ int red[THREADS];
    int b = blockIdx.x, t = threadIdx.x;
    int s = 0;
    for (int c = t; c < NCH; c += THREADS) s += cnt_mat[(size_t)b * NCH + c];
    red[t] = s;
    __syncthreads();
    for (int off = THREADS / 2; off > 0; off >>= 1) {
        if (t < off) red[t] += red[t + off];
        __syncthreads();
    }
    if (t == 0) bucket_tot[b] = red[0];
}

// K2: single block exclusive scan of NB bucket totals -> bucket_base; [NB]=E
__global__ void k_scanK2(const int* __restrict__ bucket_tot, int* __restrict__ bucket_base,
                         int NB, int E) {
    __shared__ int sh[MAXNB];
    int t = threadIdx.x;  // 512
    int v = (t < NB) ? bucket_tot[t] : 0;
    sh[t] = v;
    __syncthreads();
    for (int off = 1; off < MAXNB; off <<= 1) {
        int u = (t >= off) ? sh[t - off] : 0;
        __syncthreads();
        sh[t] += u;
        __syncthreads();
    }
    if (t < NB) bucket_base[t] = sh[t] - v;
    if (t == 0) bucket_base[NB] = E;
}

// K3: per-bucket exclusive scan over chunks + bucket base -> offs_mat
__global__ void k_scanK3(const int* __restrict__ cnt_mat, const int* __restrict__ bucket_base,
                         int* __restrict__ offs_mat, int NCH) {
    __shared__ int sh[THREADS];
    int b = blockIdx.x, t = threadIdx.x;
    int c0 = t * CPT;
    int v[CPT];
    int s = 0;
#pragma unroll
    for (int k = 0; k < CPT; ++k) {
        int c = c0 + k;
        v[k] = (c < NCH) ? cnt_mat[(size_t)b * NCH + c] : 0;
        s += v[k];
    }
    sh[t] = s;
    __syncthreads();
    for (int off = 1; off < THREADS; off <<= 1) {
        int u = (t >= off) ? sh[t - off] : 0;
        __syncthreads();
        sh[t] += u;
        __syncthreads();
    }
    int run = bucket_base[b] + sh[t] - s;
#pragma unroll
    for (int k = 0; k < CPT; ++k) {
        int c = c0 + k;
        if (c < NCH) { offs_mat[(size_t)b * NCH + c] = run; run += v[k]; }
    }
}

// Pass B: deterministic scatter. pos = offs[bucket][chunk] + lp. No atomics.
__global__ void k_scatter2(const int* __restrict__ src, const int* __restrict__ dst,
                           const unsigned short* __restrict__ lp16,
                           const int* __restrict__ offs_mat,
                           unsigned int* __restrict__ bedges, int E, int NB, int NCH) {
    __shared__ int offs[MAXNB];
    int t = threadIdx.x, chunk = blockIdx.x;
    for (int h = t; h < NB; h += THREADS) offs[h] = offs_mat[(size_t)h * NCH + chunk];
    __syncthreads();
    int e0 = chunk * CH_E, e1 = min(E, e0 + CH_E);
    for (int e = e0 + t; e < e1; e += THREADS) {
        int d = ldnt(dst + e);
        int h = d >> BSH;
        int pos = offs[h] + (int)ldnt_us(lp16 + e);
        bedges[pos] = ((unsigned int)ldnt(src + e) << BSH) | (unsigned int)(d & ((1 << BSH) - 1));
    }
}

// Block = bucket (<=256 nodes), 512 threads: LDS histogram -> rowptr, dinv;
// place srcs into csr_src.
__global__ void k_bucket_csr(const unsigned int* __restrict__ bedges,
                             const int* __restrict__ bucket_base,
                             int* __restrict__ rowptr, float* __restrict__ dinv,
                             int* __restrict__ csr_src, int N) {
    __shared__ int hist[256];
    __shared__ int sc[256];
    __shared__ int cur[256];
    int t = threadIdx.x;   // 0..511
    int b = blockIdx.x;
    int base = bucket_base[b];
    int end = bucket_base[b + 1];
    if (t < 256) hist[t] = 0;
    __syncthreads();
    for (int i = base + t; i < end; i += TCSR)
        atomicAdd(&hist[bedges[i] & 255], 1);
    __syncthreads();
    int c = 0;
    if (t < 256) { c = hist[t]; sc[t] = c; }
    __syncthreads();
    for (int off = 1; off < 256; off <<= 1) {
        int u = (t >= off && t < 256) ? sc[t - off] : 0;
        __syncthreads();
        if (t < 256) sc[t] += u;
        __syncthreads();
    }
    if (t < 256) {
        int excl = sc[t] - c;
        int node = (b << BSH) + t;
        if (node < N) {
            rowptr[node] = base + excl;
            dinv[node] = (float)(1.0 / sqrt((double)(c + 1)));
        }
        cur[t] = excl;
    }
    __syncthreads();
    for (int i = base + t; i < end; i += TCSR) {
        unsigned int u = bedges[i];
        int ln = (int)(u & 255);
        int p = atomicAdd(&cur[ln], 1);
        csr_src[base + p] = (int)(u >> BSH);
    }
}

// Row-per-thread GEMM: Hb1[n] = bf16((x[n] @ W1) * dinv[n]); W1^T staged in LDS.
__global__ __launch_bounds__(256) void k_gemm1(const float* __restrict__ X,
                        const float* __restrict__ W,
                        const float* __restrict__ dinv, unsigned short* __restrict__ H, int N) {
    __shared__ float Wt[16 * 128];   // Wt[j][k] = W[k][j]
    int t = threadIdx.x;
    for (int i = t; i < 16 * 128; i += THREADS) {
        int j = i >> 7, k = i & 127;
        Wt[i] = W[k * 16 + j];
    }
    __syncthreads();
    int row = blockIdx.x * THREADS + t;
    if (row >= N) return;
    const float* xr = X + (size_t)row * 128;
    float acc[16];
#pragma unroll
    for (int j = 0; j < 16; ++j) acc[j] = 0.0f;
#pragma unroll 4
    for (int k4 = 0; k4 < 32; ++k4) {
        float4 xv = ldnt_f4(xr + k4 * 4);   // stream-once: don't evict L2 tables
#pragma unroll
        for (int j = 0; j < 16; ++j) {
            const float4 wv = *(const float4*)&Wt[j * 128 + k4 * 4];  // uniform -> broadcast
            acc[j] += xv.x * wv.x + xv.y * wv.y + xv.z * wv.z + xv.w * wv.w;
        }
    }
    float di = dinv[row];
    uint4 oa, ob;
    oa.x = pk2bf(acc[0] * di, acc[1] * di);
    oa.y = pk2bf(acc[2] * di, acc[3] * di);
    oa.z = pk2bf(acc[4] * di, acc[5] * di);
    oa.w = pk2bf(acc[6] * di, acc[7] * di);
    ob.x = pk2bf(acc[8] * di, acc[9] * di);
    ob.y = pk2bf(acc[10] * di, acc[11] * di);
    ob.z = pk2bf(acc[12] * di, acc[13] * di);
    ob.w = pk2bf(acc[14] * di, acc[15] * di);
    uint4* outr = (uint4*)(H + (size_t)row * 16);
    outr[0] = oa;
    outr[1] = ob;
}

// Pull from bf16 table (F=16 layers): 8 features per lane (16B gathers).
// MODE 1: bf16 out = relu(t+b)*dinv   MODE 2: fp32 out = t
template<int F, int MODE>
__global__ void k_pull(const int* __restrict__ rowptr, const int* __restrict__ csr_src,
                       const float* __restrict__ dinv, const unsigned short* __restrict__ Hb,
                       const float* __restrict__ bias, void* __restrict__ outp, int N) {
    const int LPN = F / 8;
    const int NPB = THREADS / LPN;
    int node = blockIdx.x * NPB + threadIdx.x / LPN;
    int fo = (threadIdx.x % LPN) * 8;
    if (node >= N) return;
    int beg = ldnt(rowptr + node), end = ldnt(rowptr + node + 1);
    float acc[8] = {0.f, 0.f, 0.f, 0.f, 0.f, 0.f, 0.f, 0.f};
    int i = beg;
    for (; i + 4 <= end; i += 4) {
        int s0 = ldnt(csr_src + i + 0);
        int s1 = ldnt(csr_src + i + 1);
        int s2 = ldnt(csr_src + i + 2);
        int s3 = ldnt(csr_src + i + 3);
        uint4 g0 = *(const uint4*)(Hb + (size_t)s0 * F + fo);
        uint4 g1 = *(const uint4*)(Hb + (size_t)s1 * F + fo);
        uint4 g2 = *(const uint4*)(Hb + (size_t)s2 * F + fo);
        uint4 g3 = *(const uint4*)(Hb + (size_t)s3 * F + fo);
        float f0[8], f1[8], f2[8], f3[8];
        unpk8(g0, f0); unpk8(g1, f1); unpk8(g2, f2); unpk8(g3, f3);
#pragma unroll
        for (int j = 0; j < 8; ++j) acc[j] += (f0[j] + f1[j]) + (f2[j] + f3[j]);
    }
    for (; i < end; ++i) {
        int s = ldnt(csr_src + i);
        uint4 g = *(const uint4*)(Hb + (size_t)s * F + fo);
        float f[8];
        unpk8(g, f);
#pragma unroll
        for (int j = 0; j < 8; ++j) acc[j] += f[j];
    }
    uint4 gs = *(const uint4*)(Hb + (size_t)node * F + fo);
    float sf[8];
    unpk8(gs, sf);
    float di = dinv[node];
    float tv[8];
#pragma unroll
    for (int j = 0; j < 8; ++j) tv[j] = di * (acc[j] + sf[j]);
    if (MODE == 1) {
        float w[8];
#pragma unroll
        for (int j = 0; j < 8; ++j) w[j] = fmaxf(tv[j] + bias[fo + j], 0.0f) * di;
        uint4 st;
        st.x = pk2bf(w[0], w[1]); st.y = pk2bf(w[2], w[3]);
        st.z = pk2bf(w[4], w[5]); st.w = pk2bf(w[6], w[7]);
        *(uint4*)((unsigned short*)outp + (size_t)node * F + fo) = st;
    } else {
        float* of = (float*)outp + (size_t)node * F + fo;
        float4 o0, o1;
        o0.x = tv[0]; o0.y = tv[1]; o0.z = tv[2]; o0.w = tv[3];
        o1.x = tv[4]; o1.y = tv[5]; o1.z = tv[6]; o1.w = tv[7];
        ((float4*)of)[0] = o0; ((float4*)of)[1] = o1;
    }
}

// Layer-3 pull over feature-plane-split table. Blocks with (blockIdx.x&7)<4
// handle plane 0, others plane 1 (XCD round-robin heuristic -> each XCD L2
// caches one 3.2MB plane). 2 lanes per node, 8 features each.
__global__ void k_pull3(const int* __restrict__ rowptr, const int* __restrict__ csr_src,
                        const float* __restrict__ dinv,
                        const unsigned short* __restrict__ plane0,
                        const unsigned short* __restrict__ plane1,
                        const float* __restrict__ bias, float* __restrict__ h3,
                        int N, int NBLK) {
    int xcd = blockIdx.x & 7;
    int plane = xcd >> 2;
    int nb = (blockIdx.x >> 3) * 4 + (xcd & 3);
    if (nb >= NBLK) return;
    const unsigned short* Hb = plane ? plane1 : plane0;
    int node = nb * 128 + (threadIdx.x >> 1);
    int fo = (threadIdx.x & 1) * 8;
    if (node >= N) return;
    int beg = ldnt(rowptr + node), end = ldnt(rowptr + node + 1);
    float acc[8] = {0.f, 0.f, 0.f, 0.f, 0.f, 0.f, 0.f, 0.f};
    int i = beg;
    for (; i + 4 <= end; i += 4) {
        int s0 = ldnt(csr_src + i + 0);
        int s1 = ldnt(csr_src + i + 1);
        int s2 = ldnt(csr_src + i + 2);
        int s3 = ldnt(csr_src + i + 3);
        uint4 g0 = *(const uint4*)(Hb + (size_t)s0 * 16 + fo);
        uint4 g1 = *(const uint4*)(Hb + (size_t)s1 * 16 + fo);
        uint4 g2 = *(const uint4*)(Hb + (size_t)s2 * 16 + fo);
        uint4 g3 = *(const uint4*)(Hb + (size_t)s3 * 16 + fo);
        float f0[8], f1[8], f2[8], f3[8];
        unpk8(g0, f0); unpk8(g1, f1); unpk8(g2, f2); unpk8(g3, f3);
#pragma unroll
        for (int j = 0; j < 8; ++j) acc[j] += (f0[j] + f1[j]) + (f2[j] + f3[j]);
    }
    for (; i < end; ++i) {
        int s = ldnt(csr_src + i);
        uint4 g = *(const uint4*)(Hb + (size_t)s * 16 + fo);
        float f[8];
        unpk8(g, f);
#pragma unroll
        for (int j = 0; j < 8; ++j) acc[j] += f[j];
    }
    uint4 gs = *(const uint4*)(Hb + (size_t)node * 16 + fo);
    float sf[8];
    unpk8(gs, sf);
    float di = dinv[node];
    int fbase = plane * 16 + fo;
    float4 o0, o1;
    o0.x = di * (acc[0] + sf[0]) + bias[fbase + 0];
    o0.y = di * (acc[1] + sf[1]) + bias[fbase + 1];
    o0.z = di * (acc[2] + sf[2]) + bias[fbase + 2];
    o0.w = di * (acc[3] + sf[3]) + bias[fbase + 3];
    o1.x = di * (acc[4] + sf[4]) + bias[fbase + 4];
    o1.y = di * (acc[5] + sf[5]) + bias[fbase + 5];
    o1.z = di * (acc[6] + sf[6]) + bias[fbase + 6];
    o1.w = di * (acc[7] + sf[7]) + bias[fbase + 7];
    float* of = h3 + (size_t)node * 32 + fbase;
    stnt_f4(of, o0);
    stnt_f4(of + 4, o1);
}

// Register MLP: one thread per node; outputs split into two feature planes.
__global__ __launch_bounds__(256) void k_mlp(const float* __restrict__ P2,
                      const float* __restrict__ W2, const float* __restrict__ b2,
                      const float* __restrict__ W3, const float* __restrict__ dinv,
                      unsigned short* __restrict__ Hb3a, unsigned short* __restrict__ Hb3b, int N) {
    __shared__ float W2t[64][16];   // W2t[j][k] = W2[k][j]
    __shared__ float W3t[32][64];   // W3t[m][j] = W3[j][m]
    __shared__ float b2s[64];
    int t = threadIdx.x;
    for (int i = t; i < 64 * 16; i += THREADS) W2t[i / 16][i % 16] = W2[(i % 16) * 64 + (i / 16)];
    for (int i = t; i < 32 * 64; i += THREADS) W3t[i / 64][i % 64] = W3[(i % 64) * 32 + (i / 64)];
    if (t < 64) b2s[t] = b2[t];
    __syncthreads();
    int n = blockIdx.x * THREADS + t;
    if (n >= N) return;
    const float* prf = P2 + (size_t)n * 16;
    float4 p0 = ldnt_f4(prf), p1 = ldnt_f4(prf + 4), p2v = ldnt_f4(prf + 8), p3 = ldnt_f4(prf + 12);
    float p[16] = { p0.x, p0.y, p0.z, p0.w, p1.x, p1.y, p1.z, p1.w,
                    p2v.x, p2v.y, p2v.z, p2v.w, p3.x, p3.y, p3.z, p3.w };
    float a[64];
#pragma unroll
    for (int j = 0; j < 64; ++j) {
        const float4* w = (const float4*)W2t[j];  // wave-uniform -> LDS broadcast
        float4 w0 = w[0], w1 = w[1], w2q = w[2], w3q = w[3];
        float acc = b2s[j];
        acc += p[0] * w0.x + p[1] * w0.y + p[2] * w0.z + p[3] * w0.w;
        acc += p[4] * w1.x + p[5] * w1.y + p[6] * w1.z + p[7] * w1.w;
        acc += p[8] * w2q.x + p[9] * w2q.y + p[10] * w2q.z + p[11] * w2q.w;
        acc += p[12] * w3q.x + p[13] * w3q.y + p[14] * w3q.z + p[15] * w3q.w;
        a[j] = fmaxf(acc, 0.0f);
    }
    float di = dinv[n];
    unsigned short* pla = Hb3a + (size_t)n * 16;
    unsigned short* plb = Hb3b + (size_t)n * 16;
#pragma unroll
    for (int m = 0; m < 32; m += 2) {
        float o0 = 0.0f, o1 = 0.0f;
        const float4* wa = (const float4*)W3t[m];
        const float4* wb = (const float4*)W3t[m + 1];
#pragma unroll
        for (int q = 0; q < 16; ++q) {
            float4 va = wa[q], vb = wb[q];
            o0 += a[4 * q] * va.x + a[4 * q + 1] * va.y + a[4 * q + 2] * va.z + a[4 * q + 3] * va.w;
            o1 += a[4 * q] * vb.x + a[4 * q + 1] * vb.y + a[4 * q + 2] * vb.z + a[4 * q + 3] * vb.w;
        }
        unsigned int v = pk2bf(o0 * di, o1 * di);
        if (m < 16) *(unsigned int*)(pla + m) = v;
        else        *(unsigned int*)(plb + (m - 16)) = v;
    }
}

__global__ void k_zero_f(float* p, int n) {
    int i = blockIdx.x * blockDim.x + threadIdx.x;
    if (i < n) p[i] = 0.0f;
}

// Parallel segmented pooling: run-length accumulate, atomic on graph boundary.
__global__ void k_pool_part(const float* __restrict__ h3, const int* __restrict__ batch,
                            float* __restrict__ sums, int N) {
    int f = threadIdx.x & 31;
    int sub = threadIdx.x >> 5;   // 8 node-lanes
    int n0 = blockIdx.x * POOL_C;
    int n1 = min(N, n0 + POOL_C);
    float acc = 0.0f;
    int curg = -1;
    for (int n = n0 + sub; n < n1; n += 8) {
        int g = batch[n];
        if (g != curg) {
            if (curg >= 0) atomicAdd(&sums[curg * 32 + f], acc);
            acc = 0.0f;
            curg = g;
        }
        acc += ldnt_f(h3 + (size_t)n * 32 + f);
    }
    if (curg >= 0) atomicAdd(&sums[curg * 32 + f], acc);
}

// Head: cnt via binary search; a=relu(pooled@Wa+ba); out=tanh(a@Wo+bo)
__global__ void k_head(const float* __restrict__ sums, const int* __restrict__ batch, int N,
                       const float* __restrict__ Wa, const float* __restrict__ ba,
                       const float* __restrict__ Wo, const float* __restrict__ bo,
                       float* __restrict__ out) {
    int g = blockIdx.x;
    int j = threadIdx.x;  // 64 threads
    int lo = 0, hi = N;
    while (lo < hi) { int m = (lo + hi) >> 1; if (batch[m] < g) lo = m + 1; else hi = m; }
    int start = lo;
    lo = start; hi = N;
    while (lo < hi) { int m = (lo + hi) >> 1; if (batch[m] < g + 1) lo = m + 1; else hi = m; }
    int cnt = lo - start;
    float inv = 1.0f / (float)(cnt > 0 ? cnt : 1);

    __shared__ float p[32];
    __shared__ float a[64];
    if (j < 32) p[j] = sums[g * 32 + j] * inv;
    __syncthreads();
    float acc = ba[j];
#pragma unroll
    for (int k = 0; k < 32; ++k) acc += p[k] * Wa[k * 64 + j];
    a[j] = fmaxf(acc, 0.0f);
    __syncthreads();
    if (j < 32) {
        float acc2 = bo[j];
#pragma unroll
        for (int k = 0; k < 64; ++k) acc2 += a[k] * Wo[k * 32 + j];
        out[g * 32 + j] = tanhf(acc2);
    }
}

static inline int cdiv(long long a, int b) { return (int)((a + b - 1) / b); }
static inline size_t align256(size_t x) { return (x + 255) & ~(size_t)255; }

extern "C" void kernel_launch(void* const* d_in, const int* in_sizes, int n_in,
                              void* d_out, int out_size, void* d_ws, size_t ws_size,
                              hipStream_t stream) {
    const float* x     = (const float*)d_in[0];
    const int*   edge  = (const int*)d_in[1];
    const int*   batch = (const int*)d_in[2];
    const float* W1 = (const float*)d_in[3];  const float* b1 = (const float*)d_in[4];
    const float* W2 = (const float*)d_in[5];  const float* b2 = (const float*)d_in[6];
    const float* W3 = (const float*)d_in[7];  const float* b3 = (const float*)d_in[8];
    const float* Wa = (const float*)d_in[9];  const float* ba = (const float*)d_in[10];
    const float* Wo = (const float*)d_in[11]; const float* bo = (const float*)d_in[12];

    const int E = in_sizes[1] / 2;
    const int N = in_sizes[2];
    const int G = 64;
    const int NB = cdiv(N, 1 << BSH);     // 391
    const int NCH = cdiv(E, CH_E);        // 1563

    const int* srcp = edge;
    const int* dstp = edge + E;

    // Workspace
    char* base = (char*)d_ws;
    size_t off = 0;
    float* dinv   = (float*)(base + off); off = align256(off + sizeof(float) * N);
    unsigned short* lp16 = (unsigned short*)(base + off); off = align256(off + sizeof(short) * E);
    int* cnt_mat  = (int*)(base + off); off = align256(off + sizeof(int) * (size_t)NB * NCH);
    int* offs_mat = (int*)(base + off); off = align256(off + sizeof(int) * (size_t)NB * NCH);
    int* btot     = (int*)(base + off); off = align256(off + sizeof(int) * (NB + 1));
    int* bbase    = (int*)(base + off); off = align256(off + sizeof(int) * (NB + 1));
    unsigned int* bedges = (unsigned int*)(base + off); off = align256(off + sizeof(int) * E);
    int* rowptr   = (int*)(base + off); off = align256(off + sizeof(int) * (N + 1));
    int* csr_src  = (int*)(base + off); off = align256(off + sizeof(int) * E);
    unsigned short* Hb1 = (unsigned short*)(base + off); off = align256(off + sizeof(short) * (size_t)N * 16);
    unsigned short* Hb2 = (unsigned short*)(base + off); off = align256(off + sizeof(short) * (size_t)N * 16);
    float* P2     = (float*)(base + off); off = align256(off + sizeof(float) * (size_t)N * 16);
    unsigned short* Hb3a = (unsigned short*)(base + off); off = align256(off + sizeof(short) * (size_t)N * 16);
    unsigned short* Hb3b = (unsigned short*)(base + off); off = align256(off + sizeof(short) * (size_t)N * 16);
    float* h3     = (float*)(base + off); off = align256(off + sizeof(float) * (size_t)N * 32);
    float* sums   = (float*)(base + off); off = align256(off + sizeof(float) * G * 32);

    // ---- Atomic-free binning -> bucket-sorted bedges ----
    k_countA<<<NCH, THREADS, 0, stream>>>(dstp, lp16, cnt_mat, E, NB, NCH);
    k_sumK1<<<NB, THREADS, 0, stream>>>(cnt_mat, btot, NCH);
    k_scanK2<<<1, MAXNB, 0, stream>>>(btot, bbase, NB, E);
    k_scanK3<<<NB, THREADS, 0, stream>>>(cnt_mat, bbase, offs_mat, NCH);
    k_scatter2<<<NCH, THREADS, 0, stream>>>(srcp, dstp, lp16, offs_mat, bedges, E, NB, NCH);

    // ---- CSR (rowptr, csr_src, dinv) from bucket-sorted edges ----
    k_bucket_csr<<<NB, TCSR, 0, stream>>>(bedges, bbase, rowptr, dinv, csr_src, N);

    // ---- Layer 1: Hb1 = bf16((x@W1)*dinv); pull16 -> Hb2 = bf16(relu(.+b1)*dinv) ----
    k_gemm1<<<cdiv(N, THREADS), THREADS, 0, stream>>>(x, W1, dinv, Hb1, N);
    k_pull<16, 1><<<cdiv(N, 128), THREADS, 0, stream>>>(rowptr, csr_src, dinv, Hb1, b1, Hb2, N);

    // ---- Layer 2 aggregate at input width: P2 = pull16(Hb2) ----
    k_pull<16, 2><<<cdiv(N, 128), THREADS, 0, stream>>>(rowptr, csr_src, dinv, Hb2, b1 /*unused*/, P2, N);

    // ---- Fused node MLP: plane-split Hb3 = bf16((relu(P2@W2+b2)@W3)*dinv) ----
    k_mlp<<<cdiv(N, THREADS), THREADS, 0, stream>>>(P2, W2, b2, W3, dinv, Hb3a, Hb3b, N);

    // ---- Layer 3 aggregate: h3 = pull(plane-split Hb3) + b3, XCD-swizzled ----
    const int NBLK3 = cdiv(N, 128);
    k_pull3<<<8 * cdiv(NBLK3, 4), THREADS, 0, stream>>>(rowptr, csr_src, dinv, Hb3a, Hb3b, b3, h3, N, NBLK3);

    // ---- Pool (parallel, run-length atomics) + head ----
    k_zero_f<<<cdiv(G * 32, THREADS), THREADS, 0, stream>>>(sums, G * 32);
    k_pool_part<<<cdiv(N, POOL_C), THREADS, 0, stream>>>(h3, batch, sums, N);
    k_head<<<G, 64, 0, stream>>>(sums, batch, N, Wa, ba, Wo, bo, (float*)d_out);
}

// Round 11
// 424.690 us; speedup vs baseline: 1.1492x; 1.1492x over previous
//
#include <hip/hip_runtime.h>
#include <hip/hip_bf16.h>
#include <math.h>

// ActorGNN R11: R9 backbone (no NT, no XCD swizzle) + layer-3 table split into
// two 3.2MB planes pulled in two full-grid passes (each plane fits any XCD L2)
// + pipelined index prefetch in pulls. N=100000, E=3200000, G=64.

#define THREADS 256
#define TCSR 512
#define BSH 8
#define MAXNB 512
#define CH_E 2048
#define CPT 8
#define POOL_C 512

// ---- bf16 helpers ----
__device__ inline unsigned short f2bf(float f) {
    unsigned int u = __float_as_uint(f);
    return (unsigned short)((u + 0x7fffu + ((u >> 16) & 1u)) >> 16);  // RNE
}
__device__ inline unsigned int pk2bf(float a, float b) {
    return (unsigned int)f2bf(a) | ((unsigned int)f2bf(b) << 16);
}
__device__ inline float bflo(unsigned int u) { return __uint_as_float(u << 16); }
__device__ inline float bfhi(unsigned int u) { return __uint_as_float(u & 0xffff0000u); }
__device__ inline void unpk8(const uint4 u, float* f) {
    f[0] = bflo(u.x); f[1] = bfhi(u.x); f[2] = bflo(u.y); f[3] = bfhi(u.y);
    f[4] = bflo(u.z); f[5] = bfhi(u.z); f[6] = bflo(u.w); f[7] = bfhi(u.w);
}

// ---- Atomic-free binning: pass A counts + records local position ----
__global__ void k_countA(const int* __restrict__ dst, unsigned short* __restrict__ lp16,
                         int* __restrict__ cnt_mat, int E, int NB, int NCH) {
    __shared__ int hist[MAXNB];
    int t = threadIdx.x, chunk = blockIdx.x;
    for (int h = t; h < NB; h += THREADS) hist[h] = 0;
    __syncthreads();
    int e0 = chunk * CH_E, e1 = min(E, e0 + CH_E);
    for (int e = e0 + t; e < e1; e += THREADS) {
        int h = dst[e] >> BSH;
        int lp = atomicAdd(&hist[h], 1);
        lp16[e] = (unsigned short)lp;
    }
    __syncthreads();
    for (int h = t; h < NB; h += THREADS) cnt_mat[(size_t)h * NCH + chunk] = hist[h];
}

// K1: bucket totals
__global__ void k_sumK1(const int* __restrict__ cnt_mat, int* __restrict__ bucket_tot, int NCH) {
    __shared__ int red[THREADS];
    int b = blockIdx.x, t = threadIdx.x;
    int s = 0;
    for (int c = t; c < NCH; c += THREADS) s += cnt_mat[(size_t)b * NCH + c];
    red[t] = s;
    __syncthreads();
    for (int off = THREADS / 2; off > 0; off >>= 1) {
        if (t < off) red[t] += red[t + off];
        __syncthreads();
    }
    if (t == 0) bucket_tot[b] = red[0];
}

// K2: single block exclusive scan of NB bucket totals -> bucket_base; [NB]=E
__global__ void k_scanK2(const int* __restrict__ bucket_tot, int* __restrict__ bucket_base,
                         int NB, int E) {
    __shared__ int sh[MAXNB];
    int t = threadIdx.x;  // 512
    int v = (t < NB) ? bucket_tot[t] : 0;
    sh[t] = v;
    __syncthreads();
    for (int off = 1; off < MAXNB; off <<= 1) {
        int u = (t >= off) ? sh[t - off] : 0;
        __syncthreads();
        sh[t] += u;
        __syncthreads();
    }
    if (t < NB) bucket_base[t] = sh[t] - v;
    if (t == 0) bucket_base[NB] = E;
}

// K3: per-bucket exclusive scan over chunks + bucket base -> offs_mat
__global__ void k_scanK3(const int* __restrict__ cnt_mat, const int* __restrict__ bucket_base,
                         int* __restrict__ offs_mat, int NCH) {
    __shared__ int sh[THREADS];
    int b = blockIdx.x, t = threadIdx.x;
    int c0 = t * CPT;
    int v[CPT];
    int s = 0;
#pragma unroll
    for (int k = 0; k < CPT; ++k) {
        int c = c0 + k;
        v[k] = (c < NCH) ? cnt_mat[(size_t)b * NCH + c] : 0;
        s += v[k];
    }
    sh[t] = s;
    __syncthreads();
    for (int off = 1; off < THREADS; off <<= 1) {
        int u = (t >= off) ? sh[t - off] : 0;
        __syncthreads();
        sh[t] += u;
        __syncthreads();
    }
    int run = bucket_base[b] + sh[t] - s;
#pragma unroll
    for (int k = 0; k < CPT; ++k) {
        int c = c0 + k;
        if (c < NCH) { offs_mat[(size_t)b * NCH + c] = run; run += v[k]; }
    }
}

// Pass B: deterministic scatter. pos = offs[bucket][chunk] + lp. No atomics.
__global__ void k_scatter2(const int* __restrict__ src, const int* __restrict__ dst,
                           const unsigned short* __restrict__ lp16,
                           const int* __restrict__ offs_mat,
                           unsigned int* __restrict__ bedges, int E, int NB, int NCH) {
    __shared__ int offs[MAXNB];
    int t = threadIdx.x, chunk = blockIdx.x;
    for (int h = t; h < NB; h += THREADS) offs[h] = offs_mat[(size_t)h * NCH + chunk];
    __syncthreads();
    int e0 = chunk * CH_E, e1 = min(E, e0 + CH_E);
    for (int e = e0 + t; e < e1; e += THREADS) {
        int d = dst[e];
        int h = d >> BSH;
        int pos = offs[h] + (int)lp16[e];
        bedges[pos] = ((unsigned int)src[e] << BSH) | (unsigned int)(d & ((1 << BSH) - 1));
    }
}

// Block = bucket (<=256 nodes), 512 threads: LDS histogram -> rowptr, dinv;
// place srcs into csr_src.
__global__ void k_bucket_csr(const unsigned int* __restrict__ bedges,
                             const int* __restrict__ bucket_base,
                             int* __restrict__ rowptr, float* __restrict__ dinv,
                             int* __restrict__ csr_src, int N) {
    __shared__ int hist[256];
    __shared__ int sc[256];
    __shared__ int cur[256];
    int t = threadIdx.x;   // 0..511
    int b = blockIdx.x;
    int base = bucket_base[b];
    int end = bucket_base[b + 1];
    if (t < 256) hist[t] = 0;
    __syncthreads();
    for (int i = base + t; i < end; i += TCSR)
        atomicAdd(&hist[bedges[i] & 255], 1);
    __syncthreads();
    int c = 0;
    if (t < 256) { c = hist[t]; sc[t] = c; }
    __syncthreads();
    for (int off = 1; off < 256; off <<= 1) {
        int u = (t >= off && t < 256) ? sc[t - off] : 0;
        __syncthreads();
        if (t < 256) sc[t] += u;
        __syncthreads();
    }
    if (t < 256) {
        int excl = sc[t] - c;
        int node = (b << BSH) + t;
        if (node < N) {
            rowptr[node] = base + excl;
            dinv[node] = (float)(1.0 / sqrt((double)(c + 1)));
        }
        cur[t] = excl;
    }
    __syncthreads();
    for (int i = base + t; i < end; i += TCSR) {
        unsigned int u = bedges[i];
        int ln = (int)(u & 255);
        int p = atomicAdd(&cur[ln], 1);
        csr_src[base + p] = (int)(u >> BSH);
    }
}

// Row-per-thread GEMM: Hb1[n] = bf16((x[n] @ W1) * dinv[n]); W1^T staged in LDS.
__global__ __launch_bounds__(256) void k_gemm1(const float* __restrict__ X,
                        const float* __restrict__ W,
                        const float* __restrict__ dinv, unsigned short* __restrict__ H, int N) {
    __shared__ float Wt[16 * 128];   // Wt[j][k] = W[k][j]
    int t = threadIdx.x;
    for (int i = t; i < 16 * 128; i += THREADS) {
        int j = i >> 7, k = i & 127;
        Wt[i] = W[k * 16 + j];
    }
    __syncthreads();
    int row = blockIdx.x * THREADS + t;
    if (row >= N) return;
    const float4* xr = (const float4*)(X + (size_t)row * 128);
    float acc[16];
#pragma unroll
    for (int j = 0; j < 16; ++j) acc[j] = 0.0f;
#pragma unroll 4
    for (int k4 = 0; k4 < 32; ++k4) {
        float4 xv = xr[k4];
#pragma unroll
        for (int j = 0; j < 16; ++j) {
            const float4 wv = *(const float4*)&Wt[j * 128 + k4 * 4];  // uniform -> broadcast
            acc[j] += xv.x * wv.x + xv.y * wv.y + xv.z * wv.z + xv.w * wv.w;
        }
    }
    float di = dinv[row];
    uint4 oa, ob;
    oa.x = pk2bf(acc[0] * di, acc[1] * di);
    oa.y = pk2bf(acc[2] * di, acc[3] * di);
    oa.z = pk2bf(acc[4] * di, acc[5] * di);
    oa.w = pk2bf(acc[6] * di, acc[7] * di);
    ob.x = pk2bf(acc[8] * di, acc[9] * di);
    ob.y = pk2bf(acc[10] * di, acc[11] * di);
    ob.z = pk2bf(acc[12] * di, acc[13] * di);
    ob.w = pk2bf(acc[14] * di, acc[15] * di);
    uint4* outr = (uint4*)(H + (size_t)row * 16);
    outr[0] = oa;
    outr[1] = ob;
}

// Pull from bf16 table (F=16): 8 features/lane, pipelined index prefetch.
// MODE 1: bf16 out = relu(t+b)*dinv   MODE 2: fp32 out = t
template<int MODE>
__global__ void k_pull(const int* __restrict__ rowptr, const int* __restrict__ csr_src,
                       const float* __restrict__ dinv, const unsigned short* __restrict__ Hb,
                       const float* __restrict__ bias, void* __restrict__ outp, int N) {
    const int F = 16;
    int node = blockIdx.x * 128 + (threadIdx.x >> 1);
    int fo = (threadIdx.x & 1) * 8;
    if (node >= N) return;
    int beg = rowptr[node], end = rowptr[node + 1];
    float acc[8] = {0.f, 0.f, 0.f, 0.f, 0.f, 0.f, 0.f, 0.f};
    int i = beg;
    int s0, s1, s2, s3;
    if (i + 4 <= end) { s0 = csr_src[i]; s1 = csr_src[i + 1]; s2 = csr_src[i + 2]; s3 = csr_src[i + 3]; }
    for (; i + 8 <= end; i += 4) {
        int n0 = csr_src[i + 4], n1 = csr_src[i + 5], n2 = csr_src[i + 6], n3 = csr_src[i + 7];
        uint4 g0 = *(const uint4*)(Hb + (size_t)s0 * F + fo);
        uint4 g1 = *(const uint4*)(Hb + (size_t)s1 * F + fo);
        uint4 g2 = *(const uint4*)(Hb + (size_t)s2 * F + fo);
        uint4 g3 = *(const uint4*)(Hb + (size_t)s3 * F + fo);
        float f0[8], f1[8], f2[8], f3[8];
        unpk8(g0, f0); unpk8(g1, f1); unpk8(g2, f2); unpk8(g3, f3);
#pragma unroll
        for (int j = 0; j < 8; ++j) acc[j] += (f0[j] + f1[j]) + (f2[j] + f3[j]);
        s0 = n0; s1 = n1; s2 = n2; s3 = n3;
    }
    if (i + 4 <= end) {
        uint4 g0 = *(const uint4*)(Hb + (size_t)s0 * F + fo);
        uint4 g1 = *(const uint4*)(Hb + (size_t)s1 * F + fo);
        uint4 g2 = *(const uint4*)(Hb + (size_t)s2 * F + fo);
        uint4 g3 = *(const uint4*)(Hb + (size_t)s3 * F + fo);
        float f0[8], f1[8], f2[8], f3[8];
        unpk8(g0, f0); unpk8(g1, f1); unpk8(g2, f2); unpk8(g3, f3);
#pragma unroll
        for (int j = 0; j < 8; ++j) acc[j] += (f0[j] + f1[j]) + (f2[j] + f3[j]);
        i += 4;
    }
    for (; i < end; ++i) {
        int s = csr_src[i];
        uint4 g = *(const uint4*)(Hb + (size_t)s * F + fo);
        float f[8];
        unpk8(g, f);
#pragma unroll
        for (int j = 0; j < 8; ++j) acc[j] += f[j];
    }
    uint4 gs = *(const uint4*)(Hb + (size_t)node * F + fo);
    float sf[8];
    unpk8(gs, sf);
    float di = dinv[node];
    float tv[8];
#pragma unroll
    for (int j = 0; j < 8; ++j) tv[j] = di * (acc[j] + sf[j]);
    if (MODE == 1) {
        float w[8];
#pragma unroll
        for (int j = 0; j < 8; ++j) w[j] = fmaxf(tv[j] + bias[fo + j], 0.0f) * di;
        uint4 st;
        st.x = pk2bf(w[0], w[1]); st.y = pk2bf(w[2], w[3]);
        st.z = pk2bf(w[4], w[5]); st.w = pk2bf(w[6], w[7]);
        *(uint4*)((unsigned short*)outp + (size_t)node * F + fo) = st;
    } else {
        float* of = (float*)outp + (size_t)node * F + fo;
        float4 o0, o1;
        o0.x = tv[0]; o0.y = tv[1]; o0.z = tv[2]; o0.w = tv[3];
        o1.x = tv[4]; o1.y = tv[5]; o1.z = tv[6]; o1.w = tv[7];
        ((float4*)of)[0] = o0; ((float4*)of)[1] = o1;
    }
}

// Layer-3 plane pull: gather from one N×16 bf16 plane (3.2MB, L2-resident),
// write fp32 into h3 rows (stride 32) at offset fofs. Pipelined prefetch.
__global__ void k_pull3p(const int* __restrict__ rowptr, const int* __restrict__ csr_src,
                         const float* __restrict__ dinv, const unsigned short* __restrict__ plane,
                         const float* __restrict__ bias, float* __restrict__ h3,
                         int N, int fofs) {
    int node = blockIdx.x * 128 + (threadIdx.x >> 1);
    int fo = (threadIdx.x & 1) * 8;
    if (node >= N) return;
    int beg = rowptr[node], end = rowptr[node + 1];
    float acc[8] = {0.f, 0.f, 0.f, 0.f, 0.f, 0.f, 0.f, 0.f};
    int i = beg;
    int s0, s1, s2, s3;
    if (i + 4 <= end) { s0 = csr_src[i]; s1 = csr_src[i + 1]; s2 = csr_src[i + 2]; s3 = csr_src[i + 3]; }
    for (; i + 8 <= end; i += 4) {
        int n0 = csr_src[i + 4], n1 = csr_src[i + 5], n2 = csr_src[i + 6], n3 = csr_src[i + 7];
        uint4 g0 = *(const uint4*)(plane + (size_t)s0 * 16 + fo);
        uint4 g1 = *(const uint4*)(plane + (size_t)s1 * 16 + fo);
        uint4 g2 = *(const uint4*)(plane + (size_t)s2 * 16 + fo);
        uint4 g3 = *(const uint4*)(plane + (size_t)s3 * 16 + fo);
        float f0[8], f1[8], f2[8], f3[8];
        unpk8(g0, f0); unpk8(g1, f1); unpk8(g2, f2); unpk8(g3, f3);
#pragma unroll
        for (int j = 0; j < 8; ++j) acc[j] += (f0[j] + f1[j]) + (f2[j] + f3[j]);
        s0 = n0; s1 = n1; s2 = n2; s3 = n3;
    }
    if (i + 4 <= end) {
        uint4 g0 = *(const uint4*)(plane + (size_t)s0 * 16 + fo);
        uint4 g1 = *(const uint4*)(plane + (size_t)s1 * 16 + fo);
        uint4 g2 = *(const uint4*)(plane + (size_t)s2 * 16 + fo);
        uint4 g3 = *(const uint4*)(plane + (size_t)s3 * 16 + fo);
        float f0[8], f1[8], f2[8], f3[8];
        unpk8(g0, f0); unpk8(g1, f1); unpk8(g2, f2); unpk8(g3, f3);
#pragma unroll
        for (int j = 0; j < 8; ++j) acc[j] += (f0[j] + f1[j]) + (f2[j] + f3[j]);
        i += 4;
    }
    for (; i < end; ++i) {
        int s = csr_src[i];
        uint4 g = *(const uint4*)(plane + (size_t)s * 16 + fo);
        float f[8];
        unpk8(g, f);
#pragma unroll
        for (int j = 0; j < 8; ++j) acc[j] += f[j];
    }
    uint4 gs = *(const uint4*)(plane + (size_t)node * 16 + fo);
    float sf[8];
    unpk8(gs, sf);
    float di = dinv[node];
    int fb = fofs + fo;
    float4 o0, o1;
    o0.x = di * (acc[0] + sf[0]) + bias[fb + 0];
    o0.y = di * (acc[1] + sf[1]) + bias[fb + 1];
    o0.z = di * (acc[2] + sf[2]) + bias[fb + 2];
    o0.w = di * (acc[3] + sf[3]) + bias[fb + 3];
    o1.x = di * (acc[4] + sf[4]) + bias[fb + 4];
    o1.y = di * (acc[5] + sf[5]) + bias[fb + 5];
    o1.z = di * (acc[6] + sf[6]) + bias[fb + 6];
    o1.w = di * (acc[7] + sf[7]) + bias[fb + 7];
    float* of = h3 + (size_t)node * 32 + fb;
    ((float4*)of)[0] = o0;
    ((float4*)of)[1] = o1;
}

// Register MLP: one thread per node; output split into two N×16 bf16 planes.
__global__ __launch_bounds__(256) void k_mlp(const float* __restrict__ P2,
                      const float* __restrict__ W2, const float* __restrict__ b2,
                      const float* __restrict__ W3, const float* __restrict__ dinv,
                      unsigned short* __restrict__ Hb3a, unsigned short* __restrict__ Hb3b, int N) {
    __shared__ float W2t[64][16];   // W2t[j][k] = W2[k][j]
    __shared__ float W3t[32][64];   // W3t[m][j] = W3[j][m]
    __shared__ float b2s[64];
    int t = threadIdx.x;
    for (int i = t; i < 64 * 16; i += THREADS) W2t[i / 16][i % 16] = W2[(i % 16) * 64 + (i / 16)];
    for (int i = t; i < 32 * 64; i += THREADS) W3t[i / 64][i % 64] = W3[(i % 64) * 32 + (i / 64)];
    if (t < 64) b2s[t] = b2[t];
    __syncthreads();
    int n = blockIdx.x * THREADS + t;
    if (n >= N) return;
    const float4* pr = (const float4*)(P2 + (size_t)n * 16);
    float4 p0 = pr[0], p1 = pr[1], p2v = pr[2], p3 = pr[3];
    float p[16] = { p0.x, p0.y, p0.z, p0.w, p1.x, p1.y, p1.z, p1.w,
                    p2v.x, p2v.y, p2v.z, p2v.w, p3.x, p3.y, p3.z, p3.w };
    float a[64];
#pragma unroll
    for (int j = 0; j < 64; ++j) {
        const float4* w = (const float4*)W2t[j];  // wave-uniform -> LDS broadcast
        float4 w0 = w[0], w1 = w[1], w2q = w[2], w3q = w[3];
        float acc = b2s[j];
        acc += p[0] * w0.x + p[1] * w0.y + p[2] * w0.z + p[3] * w0.w;
        acc += p[4] * w1.x + p[5] * w1.y + p[6] * w1.z + p[7] * w1.w;
        acc += p[8] * w2q.x + p[9] * w2q.y + p[10] * w2q.z + p[11] * w2q.w;
        acc += p[12] * w3q.x + p[13] * w3q.y + p[14] * w3q.z + p[15] * w3q.w;
        a[j] = fmaxf(acc, 0.0f);
    }
    float di = dinv[n];
    unsigned int va[8], vb[8];
#pragma unroll
    for (int m = 0; m < 32; m += 2) {
        float o0 = 0.0f, o1 = 0.0f;
        const float4* wa = (const float4*)W3t[m];
        const float4* wb = (const float4*)W3t[m + 1];
#pragma unroll
        for (int q = 0; q < 16; ++q) {
            float4 vva = wa[q], vvb = wb[q];
            o0 += a[4 * q] * vva.x + a[4 * q + 1] * vva.y + a[4 * q + 2] * vva.z + a[4 * q + 3] * vva.w;
            o1 += a[4 * q] * vvb.x + a[4 * q + 1] * vvb.y + a[4 * q + 2] * vvb.z + a[4 * q + 3] * vvb.w;
        }
        unsigned int v = pk2bf(o0 * di, o1 * di);
        if (m < 16) va[m >> 1] = v;
        else        vb[(m - 16) >> 1] = v;
    }
    uint4* pa = (uint4*)(Hb3a + (size_t)n * 16);
    uint4* pb = (uint4*)(Hb3b + (size_t)n * 16);
    pa[0] = make_uint4(va[0], va[1], va[2], va[3]);
    pa[1] = make_uint4(va[4], va[5], va[6], va[7]);
    pb[0] = make_uint4(vb[0], vb[1], vb[2], vb[3]);
    pb[1] = make_uint4(vb[4], vb[5], vb[6], vb[7]);
}

__global__ void k_zero_f(float* p, int n) {
    int i = blockIdx.x * blockDim.x + threadIdx.x;
    if (i < n) p[i] = 0.0f;
}

// Parallel segmented pooling: run-length accumulate, atomic on graph boundary.
__global__ void k_pool_part(const float* __restrict__ h3, const int* __restrict__ batch,
                            float* __restrict__ sums, int N) {
    int f = threadIdx.x & 31;
    int sub = threadIdx.x >> 5;   // 8 node-lanes
    int n0 = blockIdx.x * POOL_C;
    int n1 = min(N, n0 + POOL_C);
    float acc = 0.0f;
    int curg = -1;
    for (int n = n0 + sub; n < n1; n += 8) {
        int g = batch[n];
        if (g != curg) {
            if (curg >= 0) atomicAdd(&sums[curg * 32 + f], acc);
            acc = 0.0f;
            curg = g;
        }
        acc += h3[(size_t)n * 32 + f];
    }
    if (curg >= 0) atomicAdd(&sums[curg * 32 + f], acc);
}

// Head: cnt via binary search; a=relu(pooled@Wa+ba); out=tanh(a@Wo+bo)
__global__ void k_head(const float* __restrict__ sums, const int* __restrict__ batch, int N,
                       const float* __restrict__ Wa, const float* __restrict__ ba,
                       const float* __restrict__ Wo, const float* __restrict__ bo,
                       float* __restrict__ out) {
    int g = blockIdx.x;
    int j = threadIdx.x;  // 64 threads
    int lo = 0, hi = N;
    while (lo < hi) { int m = (lo + hi) >> 1; if (batch[m] < g) lo = m + 1; else hi = m; }
    int start = lo;
    lo = start; hi = N;
    while (lo < hi) { int m = (lo + hi) >> 1; if (batch[m] < g + 1) lo = m + 1; else hi = m; }
    int cnt = lo - start;
    float inv = 1.0f / (float)(cnt > 0 ? cnt : 1);

    __shared__ float p[32];
    __shared__ float a[64];
    if (j < 32) p[j] = sums[g * 32 + j] * inv;
    __syncthreads();
    float acc = ba[j];
#pragma unroll
    for (int k = 0; k < 32; ++k) acc += p[k] * Wa[k * 64 + j];
    a[j] = fmaxf(acc, 0.0f);
    __syncthreads();
    if (j < 32) {
        float acc2 = bo[j];
#pragma unroll
        for (int k = 0; k < 64; ++k) acc2 += a[k] * Wo[k * 32 + j];
        out[g * 32 + j] = tanhf(acc2);
    }
}

static inline int cdiv(long long a, int b) { return (int)((a + b - 1) / b); }
static inline size_t align256(size_t x) { return (x + 255) & ~(size_t)255; }

extern "C" void kernel_launch(void* const* d_in, const int* in_sizes, int n_in,
                              void* d_out, int out_size, void* d_ws, size_t ws_size,
                              hipStream_t stream) {
    const float* x     = (const float*)d_in[0];
    const int*   edge  = (const int*)d_in[1];
    const int*   batch = (const int*)d_in[2];
    const float* W1 = (const float*)d_in[3];  const float* b1 = (const float*)d_in[4];
    const float* W2 = (const float*)d_in[5];  const float* b2 = (const float*)d_in[6];
    const float* W3 = (const float*)d_in[7];  const float* b3 = (const float*)d_in[8];
    const float* Wa = (const float*)d_in[9];  const float* ba = (const float*)d_in[10];
    const float* Wo = (const float*)d_in[11]; const float* bo = (const float*)d_in[12];

    const int E = in_sizes[1] / 2;
    const int N = in_sizes[2];
    const int G = 64;
    const int NB = cdiv(N, 1 << BSH);     // 391
    const int NCH = cdiv(E, CH_E);        // 1563

    const int* srcp = edge;
    const int* dstp = edge + E;

    // Workspace
    char* base = (char*)d_ws;
    size_t off = 0;
    float* dinv   = (float*)(base + off); off = align256(off + sizeof(float) * N);
    unsigned short* lp16 = (unsigned short*)(base + off); off = align256(off + sizeof(short) * E);
    int* cnt_mat  = (int*)(base + off); off = align256(off + sizeof(int) * (size_t)NB * NCH);
    int* offs_mat = (int*)(base + off); off = align256(off + sizeof(int) * (size_t)NB * NCH);
    int* btot     = (int*)(base + off); off = align256(off + sizeof(int) * (NB + 1));
    int* bbase    = (int*)(base + off); off = align256(off + sizeof(int) * (NB + 1));
    unsigned int* bedges = (unsigned int*)(base + off); off = align256(off + sizeof(int) * E);
    int* rowptr   = (int*)(base + off); off = align256(off + sizeof(int) * (N + 1));
    int* csr_src  = (int*)(base + off); off = align256(off + sizeof(int) * E);
    unsigned short* Hb1 = (unsigned short*)(base + off); off = align256(off + sizeof(short) * (size_t)N * 16);
    unsigned short* Hb2 = (unsigned short*)(base + off); off = align256(off + sizeof(short) * (size_t)N * 16);
    float* P2     = (float*)(base + off); off = align256(off + sizeof(float) * (size_t)N * 16);
    unsigned short* Hb3a = (unsigned short*)(base + off); off = align256(off + sizeof(short) * (size_t)N * 16);
    unsigned short* Hb3b = (unsigned short*)(base + off); off = align256(off + sizeof(short) * (size_t)N * 16);
    float* h3     = (float*)(base + off); off = align256(off + sizeof(float) * (size_t)N * 32);
    float* sums   = (float*)(base + off); off = align256(off + sizeof(float) * G * 32);

    // ---- Atomic-free binning -> bucket-sorted bedges ----
    k_countA<<<NCH, THREADS, 0, stream>>>(dstp, lp16, cnt_mat, E, NB, NCH);
    k_sumK1<<<NB, THREADS, 0, stream>>>(cnt_mat, btot, NCH);
    k_scanK2<<<1, MAXNB, 0, stream>>>(btot, bbase, NB, E);
    k_scanK3<<<NB, THREADS, 0, stream>>>(cnt_mat, bbase, offs_mat, NCH);
    k_scatter2<<<NCH, THREADS, 0, stream>>>(srcp, dstp, lp16, offs_mat, bedges, E, NB, NCH);

    // ---- CSR (rowptr, csr_src, dinv) from bucket-sorted edges ----
    k_bucket_csr<<<NB, TCSR, 0, stream>>>(bedges, bbase, rowptr, dinv, csr_src, N);

    // ---- Layer 1: Hb1 = bf16((x@W1)*dinv); pull16 -> Hb2 = bf16(relu(.+b1)*dinv) ----
    k_gemm1<<<cdiv(N, THREADS), THREADS, 0, stream>>>(x, W1, dinv, Hb1, N);
    k_pull<1><<<cdiv(N, 128), THREADS, 0, stream>>>(rowptr, csr_src, dinv, Hb1, b1, Hb2, N);

    // ---- Layer 2 aggregate at input width: P2 = pull16(Hb2) ----
    k_pull<2><<<cdiv(N, 128), THREADS, 0, stream>>>(rowptr, csr_src, dinv, Hb2, b1 /*unused*/, P2, N);

    // ---- Fused node MLP: plane-split Hb3 = bf16((relu(P2@W2+b2)@W3)*dinv) ----
    k_mlp<<<cdiv(N, THREADS), THREADS, 0, stream>>>(P2, W2, b2, W3, dinv, Hb3a, Hb3b, N);

    // ---- Layer 3 aggregate: two plane pulls (each 3.2MB table, L2-resident) ----
    k_pull3p<<<cdiv(N, 128), THREADS, 0, stream>>>(rowptr, csr_src, dinv, Hb3a, b3, h3, N, 0);
    k_pull3p<<<cdiv(N, 128), THREADS, 0, stream>>>(rowptr, csr_src, dinv, Hb3b, b3, h3, N, 16);

    // ---- Pool (parallel, run-length atomics) + head ----
    k_zero_f<<<cdiv(G * 32, THREADS), THREADS, 0, stream>>>(sums, G * 32);
    k_pool_part<<<cdiv(N, POOL_C), THREADS, 0, stream>>>(h3, batch, sums, N);
    k_head<<<G, 64, 0, stream>>>(sums, batch, N, Wa, ba, Wo, bo, (float*)d_out);
}

// Round 12
// 408.633 us; speedup vs baseline: 1.1944x; 1.0393x over previous
//
#include <hip/hip_runtime.h>
#include <hip/hip_bf16.h>
#include <math.h>

// ActorGNN R12: R11 with k_mlp reverted byte-for-byte to R9 (single N×32 out),
// plus a trivial k_split producing the two 3.2MB planes for the L2-resident
// layer-3 plane pulls. N=100000, E=3200000, G=64.

#define THREADS 256
#define TCSR 512
#define BSH 8
#define MAXNB 512
#define CH_E 2048
#define CPT 8
#define POOL_C 512

// ---- bf16 helpers ----
__device__ inline unsigned short f2bf(float f) {
    unsigned int u = __float_as_uint(f);
    return (unsigned short)((u + 0x7fffu + ((u >> 16) & 1u)) >> 16);  // RNE
}
__device__ inline unsigned int pk2bf(float a, float b) {
    return (unsigned int)f2bf(a) | ((unsigned int)f2bf(b) << 16);
}
__device__ inline float bflo(unsigned int u) { return __uint_as_float(u << 16); }
__device__ inline float bfhi(unsigned int u) { return __uint_as_float(u & 0xffff0000u); }
__device__ inline void unpk8(const uint4 u, float* f) {
    f[0] = bflo(u.x); f[1] = bfhi(u.x); f[2] = bflo(u.y); f[3] = bfhi(u.y);
    f[4] = bflo(u.z); f[5] = bfhi(u.z); f[6] = bflo(u.w); f[7] = bfhi(u.w);
}

// ---- Atomic-free binning: pass A counts + records local position ----
__global__ void k_countA(const int* __restrict__ dst, unsigned short* __restrict__ lp16,
                         int* __restrict__ cnt_mat, int E, int NB, int NCH) {
    __shared__ int hist[MAXNB];
    int t = threadIdx.x, chunk = blockIdx.x;
    for (int h = t; h < NB; h += THREADS) hist[h] = 0;
    __syncthreads();
    int e0 = chunk * CH_E, e1 = min(E, e0 + CH_E);
    for (int e = e0 + t; e < e1; e += THREADS) {
        int h = dst[e] >> BSH;
        int lp = atomicAdd(&hist[h], 1);
        lp16[e] = (unsigned short)lp;
    }
    __syncthreads();
    for (int h = t; h < NB; h += THREADS) cnt_mat[(size_t)h * NCH + chunk] = hist[h];
}

// K1: bucket totals
__global__ void k_sumK1(const int* __restrict__ cnt_mat, int* __restrict__ bucket_tot, int NCH) {
    __shared__ int red[THREADS];
    int b = blockIdx.x, t = threadIdx.x;
    int s = 0;
    for (int c = t; c < NCH; c += THREADS) s += cnt_mat[(size_t)b * NCH + c];
    red[t] = s;
    __syncthreads();
    for (int off = THREADS / 2; off > 0; off >>= 1) {
        if (t < off) red[t] += red[t + off];
        __syncthreads();
    }
    if (t == 0) bucket_tot[b] = red[0];
}

// K2: single block exclusive scan of NB bucket totals -> bucket_base; [NB]=E
__global__ void k_scanK2(const int* __restrict__ bucket_tot, int* __restrict__ bucket_base,
                         int NB, int E) {
    __shared__ int sh[MAXNB];
    int t = threadIdx.x;  // 512
    int v = (t < NB) ? bucket_tot[t] : 0;
    sh[t] = v;
    __syncthreads();
    for (int off = 1; off < MAXNB; off <<= 1) {
        int u = (t >= off) ? sh[t - off] : 0;
        __syncthreads();
        sh[t] += u;
        __syncthreads();
    }
    if (t < NB) bucket_base[t] = sh[t] - v;
    if (t == 0) bucket_base[NB] = E;
}

// K3: per-bucket exclusive scan over chunks + bucket base -> offs_mat
__global__ void k_scanK3(const int* __restrict__ cnt_mat, const int* __restrict__ bucket_base,
                         int* __restrict__ offs_mat, int NCH) {
    __shared__ int sh[THREADS];
    int b = blockIdx.x, t = threadIdx.x;
    int c0 = t * CPT;
    int v[CPT];
    int s = 0;
#pragma unroll
    for (int k = 0; k < CPT; ++k) {
        int c = c0 + k;
        v[k] = (c < NCH) ? cnt_mat[(size_t)b * NCH + c] : 0;
        s += v[k];
    }
    sh[t] = s;
    __syncthreads();
    for (int off = 1; off < THREADS; off <<= 1) {
        int u = (t >= off) ? sh[t - off] : 0;
        __syncthreads();
        sh[t] += u;
        __syncthreads();
    }
    int run = bucket_base[b] + sh[t] - s;
#pragma unroll
    for (int k = 0; k < CPT; ++k) {
        int c = c0 + k;
        if (c < NCH) { offs_mat[(size_t)b * NCH + c] = run; run += v[k]; }
    }
}

// Pass B: deterministic scatter. pos = offs[bucket][chunk] + lp. No atomics.
__global__ void k_scatter2(const int* __restrict__ src, const int* __restrict__ dst,
                           const unsigned short* __restrict__ lp16,
                           const int* __restrict__ offs_mat,
                           unsigned int* __restrict__ bedges, int E, int NB, int NCH) {
    __shared__ int offs[MAXNB];
    int t = threadIdx.x, chunk = blockIdx.x;
    for (int h = t; h < NB; h += THREADS) offs[h] = offs_mat[(size_t)h * NCH + chunk];
    __syncthreads();
    int e0 = chunk * CH_E, e1 = min(E, e0 + CH_E);
    for (int e = e0 + t; e < e1; e += THREADS) {
        int d = dst[e];
        int h = d >> BSH;
        int pos = offs[h] + (int)lp16[e];
        bedges[pos] = ((unsigned int)src[e] << BSH) | (unsigned int)(d & ((1 << BSH) - 1));
    }
}

// Block = bucket (<=256 nodes), 512 threads: LDS histogram -> rowptr, dinv;
// place srcs into csr_src.
__global__ void k_bucket_csr(const unsigned int* __restrict__ bedges,
                             const int* __restrict__ bucket_base,
                             int* __restrict__ rowptr, float* __restrict__ dinv,
                             int* __restrict__ csr_src, int N) {
    __shared__ int hist[256];
    __shared__ int sc[256];
    __shared__ int cur[256];
    int t = threadIdx.x;   // 0..511
    int b = blockIdx.x;
    int base = bucket_base[b];
    int end = bucket_base[b + 1];
    if (t < 256) hist[t] = 0;
    __syncthreads();
    for (int i = base + t; i < end; i += TCSR)
        atomicAdd(&hist[bedges[i] & 255], 1);
    __syncthreads();
    int c = 0;
    if (t < 256) { c = hist[t]; sc[t] = c; }
    __syncthreads();
    for (int off = 1; off < 256; off <<= 1) {
        int u = (t >= off && t < 256) ? sc[t - off] : 0;
        __syncthreads();
        if (t < 256) sc[t] += u;
        __syncthreads();
    }
    if (t < 256) {
        int excl = sc[t] - c;
        int node = (b << BSH) + t;
        if (node < N) {
            rowptr[node] = base + excl;
            dinv[node] = (float)(1.0 / sqrt((double)(c + 1)));
        }
        cur[t] = excl;
    }
    __syncthreads();
    for (int i = base + t; i < end; i += TCSR) {
        unsigned int u = bedges[i];
        int ln = (int)(u & 255);
        int p = atomicAdd(&cur[ln], 1);
        csr_src[base + p] = (int)(u >> BSH);
    }
}

// Row-per-thread GEMM: Hb1[n] = bf16((x[n] @ W1) * dinv[n]); W1^T staged in LDS.
__global__ __launch_bounds__(256) void k_gemm1(const float* __restrict__ X,
                        const float* __restrict__ W,
                        const float* __restrict__ dinv, unsigned short* __restrict__ H, int N) {
    __shared__ float Wt[16 * 128];   // Wt[j][k] = W[k][j]
    int t = threadIdx.x;
    for (int i = t; i < 16 * 128; i += THREADS) {
        int j = i >> 7, k = i & 127;
        Wt[i] = W[k * 16 + j];
    }
    __syncthreads();
    int row = blockIdx.x * THREADS + t;
    if (row >= N) return;
    const float4* xr = (const float4*)(X + (size_t)row * 128);
    float acc[16];
#pragma unroll
    for (int j = 0; j < 16; ++j) acc[j] = 0.0f;
#pragma unroll 4
    for (int k4 = 0; k4 < 32; ++k4) {
        float4 xv = xr[k4];
#pragma unroll
        for (int j = 0; j < 16; ++j) {
            const float4 wv = *(const float4*)&Wt[j * 128 + k4 * 4];  // uniform -> broadcast
            acc[j] += xv.x * wv.x + xv.y * wv.y + xv.z * wv.z + xv.w * wv.w;
        }
    }
    float di = dinv[row];
    uint4 oa, ob;
    oa.x = pk2bf(acc[0] * di, acc[1] * di);
    oa.y = pk2bf(acc[2] * di, acc[3] * di);
    oa.z = pk2bf(acc[4] * di, acc[5] * di);
    oa.w = pk2bf(acc[6] * di, acc[7] * di);
    ob.x = pk2bf(acc[8] * di, acc[9] * di);
    ob.y = pk2bf(acc[10] * di, acc[11] * di);
    ob.z = pk2bf(acc[12] * di, acc[13] * di);
    ob.w = pk2bf(acc[14] * di, acc[15] * di);
    uint4* outr = (uint4*)(H + (size_t)row * 16);
    outr[0] = oa;
    outr[1] = ob;
}

// Pull from bf16 table (F=16): 8 features/lane, pipelined index prefetch.
// MODE 1: bf16 out = relu(t+b)*dinv   MODE 2: fp32 out = t
template<int MODE>
__global__ void k_pull(const int* __restrict__ rowptr, const int* __restrict__ csr_src,
                       const float* __restrict__ dinv, const unsigned short* __restrict__ Hb,
                       const float* __restrict__ bias, void* __restrict__ outp, int N) {
    const int F = 16;
    int node = blockIdx.x * 128 + (threadIdx.x >> 1);
    int fo = (threadIdx.x & 1) * 8;
    if (node >= N) return;
    int beg = rowptr[node], end = rowptr[node + 1];
    float acc[8] = {0.f, 0.f, 0.f, 0.f, 0.f, 0.f, 0.f, 0.f};
    int i = beg;
    int s0, s1, s2, s3;
    if (i + 4 <= end) { s0 = csr_src[i]; s1 = csr_src[i + 1]; s2 = csr_src[i + 2]; s3 = csr_src[i + 3]; }
    for (; i + 8 <= end; i += 4) {
        int n0 = csr_src[i + 4], n1 = csr_src[i + 5], n2 = csr_src[i + 6], n3 = csr_src[i + 7];
        uint4 g0 = *(const uint4*)(Hb + (size_t)s0 * F + fo);
        uint4 g1 = *(const uint4*)(Hb + (size_t)s1 * F + fo);
        uint4 g2 = *(const uint4*)(Hb + (size_t)s2 * F + fo);
        uint4 g3 = *(const uint4*)(Hb + (size_t)s3 * F + fo);
        float f0[8], f1[8], f2[8], f3[8];
        unpk8(g0, f0); unpk8(g1, f1); unpk8(g2, f2); unpk8(g3, f3);
#pragma unroll
        for (int j = 0; j < 8; ++j) acc[j] += (f0[j] + f1[j]) + (f2[j] + f3[j]);
        s0 = n0; s1 = n1; s2 = n2; s3 = n3;
    }
    if (i + 4 <= end) {
        uint4 g0 = *(const uint4*)(Hb + (size_t)s0 * F + fo);
        uint4 g1 = *(const uint4*)(Hb + (size_t)s1 * F + fo);
        uint4 g2 = *(const uint4*)(Hb + (size_t)s2 * F + fo);
        uint4 g3 = *(const uint4*)(Hb + (size_t)s3 * F + fo);
        float f0[8], f1[8], f2[8], f3[8];
        unpk8(g0, f0); unpk8(g1, f1); unpk8(g2, f2); unpk8(g3, f3);
#pragma unroll
        for (int j = 0; j < 8; ++j) acc[j] += (f0[j] + f1[j]) + (f2[j] + f3[j]);
        i += 4;
    }
    for (; i < end; ++i) {
        int s = csr_src[i];
        uint4 g = *(const uint4*)(Hb + (size_t)s * F + fo);
        float f[8];
        unpk8(g, f);
#pragma unroll
        for (int j = 0; j < 8; ++j) acc[j] += f[j];
    }
    uint4 gs = *(const uint4*)(Hb + (size_t)node * F + fo);
    float sf[8];
    unpk8(gs, sf);
    float di = dinv[node];
    float tv[8];
#pragma unroll
    for (int j = 0; j < 8; ++j) tv[j] = di * (acc[j] + sf[j]);
    if (MODE == 1) {
        float w[8];
#pragma unroll
        for (int j = 0; j < 8; ++j) w[j] = fmaxf(tv[j] + bias[fo + j], 0.0f) * di;
        uint4 st;
        st.x = pk2bf(w[0], w[1]); st.y = pk2bf(w[2], w[3]);
        st.z = pk2bf(w[4], w[5]); st.w = pk2bf(w[6], w[7]);
        *(uint4*)((unsigned short*)outp + (size_t)node * F + fo) = st;
    } else {
        float* of = (float*)outp + (size_t)node * F + fo;
        float4 o0, o1;
        o0.x = tv[0]; o0.y = tv[1]; o0.z = tv[2]; o0.w = tv[3];
        o1.x = tv[4]; o1.y = tv[5]; o1.z = tv[6]; o1.w = tv[7];
        ((float4*)of)[0] = o0; ((float4*)of)[1] = o1;
    }
}

// Layer-3 plane pull: gather from one N×16 bf16 plane (3.2MB, L2-resident),
// write fp32 into h3 rows (stride 32) at offset fofs. Pipelined prefetch.
__global__ void k_pull3p(const int* __restrict__ rowptr, const int* __restrict__ csr_src,
                         const float* __restrict__ dinv, const unsigned short* __restrict__ plane,
                         const float* __restrict__ bias, float* __restrict__ h3,
                         int N, int fofs) {
    int node = blockIdx.x * 128 + (threadIdx.x >> 1);
    int fo = (threadIdx.x & 1) * 8;
    if (node >= N) return;
    int beg = rowptr[node], end = rowptr[node + 1];
    float acc[8] = {0.f, 0.f, 0.f, 0.f, 0.f, 0.f, 0.f, 0.f};
    int i = beg;
    int s0, s1, s2, s3;
    if (i + 4 <= end) { s0 = csr_src[i]; s1 = csr_src[i + 1]; s2 = csr_src[i + 2]; s3 = csr_src[i + 3]; }
    for (; i + 8 <= end; i += 4) {
        int n0 = csr_src[i + 4], n1 = csr_src[i + 5], n2 = csr_src[i + 6], n3 = csr_src[i + 7];
        uint4 g0 = *(const uint4*)(plane + (size_t)s0 * 16 + fo);
        uint4 g1 = *(const uint4*)(plane + (size_t)s1 * 16 + fo);
        uint4 g2 = *(const uint4*)(plane + (size_t)s2 * 16 + fo);
        uint4 g3 = *(const uint4*)(plane + (size_t)s3 * 16 + fo);
        float f0[8], f1[8], f2[8], f3[8];
        unpk8(g0, f0); unpk8(g1, f1); unpk8(g2, f2); unpk8(g3, f3);
#pragma unroll
        for (int j = 0; j < 8; ++j) acc[j] += (f0[j] + f1[j]) + (f2[j] + f3[j]);
        s0 = n0; s1 = n1; s2 = n2; s3 = n3;
    }
    if (i + 4 <= end) {
        uint4 g0 = *(const uint4*)(plane + (size_t)s0 * 16 + fo);
        uint4 g1 = *(const uint4*)(plane + (size_t)s1 * 16 + fo);
        uint4 g2 = *(const uint4*)(plane + (size_t)s2 * 16 + fo);
        uint4 g3 = *(const uint4*)(plane + (size_t)s3 * 16 + fo);
        float f0[8], f1[8], f2[8], f3[8];
        unpk8(g0, f0); unpk8(g1, f1); unpk8(g2, f2); unpk8(g3, f3);
#pragma unroll
        for (int j = 0; j < 8; ++j) acc[j] += (f0[j] + f1[j]) + (f2[j] + f3[j]);
        i += 4;
    }
    for (; i < end; ++i) {
        int s = csr_src[i];
        uint4 g = *(const uint4*)(plane + (size_t)s * 16 + fo);
        float f[8];
        unpk8(g, f);
#pragma unroll
        for (int j = 0; j < 8; ++j) acc[j] += f[j];
    }
    uint4 gs = *(const uint4*)(plane + (size_t)node * 16 + fo);
    float sf[8];
    unpk8(gs, sf);
    float di = dinv[node];
    int fb = fofs + fo;
    float4 o0, o1;
    o0.x = di * (acc[0] + sf[0]) + bias[fb + 0];
    o0.y = di * (acc[1] + sf[1]) + bias[fb + 1];
    o0.z = di * (acc[2] + sf[2]) + bias[fb + 2];
    o0.w = di * (acc[3] + sf[3]) + bias[fb + 3];
    o1.x = di * (acc[4] + sf[4]) + bias[fb + 4];
    o1.y = di * (acc[5] + sf[5]) + bias[fb + 5];
    o1.z = di * (acc[6] + sf[6]) + bias[fb + 6];
    o1.w = di * (acc[7] + sf[7]) + bias[fb + 7];
    float* of = h3 + (size_t)node * 32 + fb;
    ((float4*)of)[0] = o0;
    ((float4*)of)[1] = o1;
}

// Register MLP (exact R9 form): one thread per node, single N×32 bf16 output.
__global__ __launch_bounds__(256) void k_mlp(const float* __restrict__ P2,
                      const float* __restrict__ W2, const float* __restrict__ b2,
                      const float* __restrict__ W3, const float* __restrict__ dinv,
                      unsigned short* __restrict__ Hb3, int N) {
    __shared__ float W2t[64][16];   // W2t[j][k] = W2[k][j]
    __shared__ float W3t[32][64];   // W3t[m][j] = W3[j][m]
    __shared__ float b2s[64];
    int t = threadIdx.x;
    for (int i = t; i < 64 * 16; i += THREADS) W2t[i / 16][i % 16] = W2[(i % 16) * 64 + (i / 16)];
    for (int i = t; i < 32 * 64; i += THREADS) W3t[i / 64][i % 64] = W3[(i % 64) * 32 + (i / 64)];
    if (t < 64) b2s[t] = b2[t];
    __syncthreads();
    int n = blockIdx.x * THREADS + t;
    if (n >= N) return;
    const float4* pr = (const float4*)(P2 + (size_t)n * 16);
    float4 p0 = pr[0], p1 = pr[1], p2v = pr[2], p3 = pr[3];
    float p[16] = { p0.x, p0.y, p0.z, p0.w, p1.x, p1.y, p1.z, p1.w,
                    p2v.x, p2v.y, p2v.z, p2v.w, p3.x, p3.y, p3.z, p3.w };
    float a[64];
#pragma unroll
    for (int j = 0; j < 64; ++j) {
        const float4* w = (const float4*)W2t[j];  // wave-uniform -> LDS broadcast
        float4 w0 = w[0], w1 = w[1], w2q = w[2], w3q = w[3];
        float acc = b2s[j];
        acc += p[0] * w0.x + p[1] * w0.y + p[2] * w0.z + p[3] * w0.w;
        acc += p[4] * w1.x + p[5] * w1.y + p[6] * w1.z + p[7] * w1.w;
        acc += p[8] * w2q.x + p[9] * w2q.y + p[10] * w2q.z + p[11] * w2q.w;
        acc += p[12] * w3q.x + p[13] * w3q.y + p[14] * w3q.z + p[15] * w3q.w;
        a[j] = fmaxf(acc, 0.0f);
    }
    float di = dinv[n];
    unsigned short* outr = Hb3 + (size_t)n * 32;
#pragma unroll
    for (int m = 0; m < 32; m += 2) {
        float o0 = 0.0f, o1 = 0.0f;
        const float4* wa = (const float4*)W3t[m];
        const float4* wb = (const float4*)W3t[m + 1];
#pragma unroll
        for (int q = 0; q < 16; ++q) {
            float4 va = wa[q], vb = wb[q];
            o0 += a[4 * q] * va.x + a[4 * q + 1] * va.y + a[4 * q + 2] * va.z + a[4 * q + 3] * va.w;
            o1 += a[4 * q] * vb.x + a[4 * q + 1] * vb.y + a[4 * q + 2] * vb.z + a[4 * q + 3] * vb.w;
        }
        *(unsigned int*)(outr + m) = pk2bf(o0 * di, o1 * di);
    }
}

// Split N×32 table into two N×16 planes (bandwidth-trivial).
__global__ void k_split(const unsigned short* __restrict__ Hb3,
                        unsigned short* __restrict__ A, unsigned short* __restrict__ B, int N) {
    int n = blockIdx.x * blockDim.x + threadIdx.x;
    if (n >= N) return;
    const uint4* r = (const uint4*)(Hb3 + (size_t)n * 32);
    uint4 q0 = r[0], q1 = r[1], q2 = r[2], q3 = r[3];
    uint4* pa = (uint4*)(A + (size_t)n * 16);
    uint4* pb = (uint4*)(B + (size_t)n * 16);
    pa[0] = q0; pa[1] = q1;
    pb[0] = q2; pb[1] = q3;
}

__global__ void k_zero_f(float* p, int n) {
    int i = blockIdx.x * blockDim.x + threadIdx.x;
    if (i < n) p[i] = 0.0f;
}

// Parallel segmented pooling: run-length accumulate, atomic on graph boundary.
__global__ void k_pool_part(const float* __restrict__ h3, const int* __restrict__ batch,
                            float* __restrict__ sums, int N) {
    int f = threadIdx.x & 31;
    int sub = threadIdx.x >> 5;   // 8 node-lanes
    int n0 = blockIdx.x * POOL_C;
    int n1 = min(N, n0 + POOL_C);
    float acc = 0.0f;
    int curg = -1;
    for (int n = n0 + sub; n < n1; n += 8) {
        int g = batch[n];
        if (g != curg) {
            if (curg >= 0) atomicAdd(&sums[curg * 32 + f], acc);
            acc = 0.0f;
            curg = g;
        }
        acc += h3[(size_t)n * 32 + f];
    }
    if (curg >= 0) atomicAdd(&sums[curg * 32 + f], acc);
}

// Head: cnt via binary search; a=relu(pooled@Wa+ba); out=tanh(a@Wo+bo)
__global__ void k_head(const float* __restrict__ sums, const int* __restrict__ batch, int N,
                       const float* __restrict__ Wa, const float* __restrict__ ba,
                       const float* __restrict__ Wo, const float* __restrict__ bo,
                       float* __restrict__ out) {
    int g = blockIdx.x;
    int j = threadIdx.x;  // 64 threads
    int lo = 0, hi = N;
    while (lo < hi) { int m = (lo + hi) >> 1; if (batch[m] < g) lo = m + 1; else hi = m; }
    int start = lo;
    lo = start; hi = N;
    while (lo < hi) { int m = (lo + hi) >> 1; if (batch[m] < g + 1) lo = m + 1; else hi = m; }
    int cnt = lo - start;
    float inv = 1.0f / (float)(cnt > 0 ? cnt : 1);

    __shared__ float p[32];
    __shared__ float a[64];
    if (j < 32) p[j] = sums[g * 32 + j] * inv;
    __syncthreads();
    float acc = ba[j];
#pragma unroll
    for (int k = 0; k < 32; ++k) acc += p[k] * Wa[k * 64 + j];
    a[j] = fmaxf(acc, 0.0f);
    __syncthreads();
    if (j < 32) {
        float acc2 = bo[j];
#pragma unroll
        for (int k = 0; k < 64; ++k) acc2 += a[k] * Wo[k * 32 + j];
        out[g * 32 + j] = tanhf(acc2);
    }
}

static inline int cdiv(long long a, int b) { return (int)((a + b - 1) / b); }
static inline size_t align256(size_t x) { return (x + 255) & ~(size_t)255; }

extern "C" void kernel_launch(void* const* d_in, const int* in_sizes, int n_in,
                              void* d_out, int out_size, void* d_ws, size_t ws_size,
                              hipStream_t stream) {
    const float* x     = (const float*)d_in[0];
    const int*   edge  = (const int*)d_in[1];
    const int*   batch = (const int*)d_in[2];
    const float* W1 = (const float*)d_in[3];  const float* b1 = (const float*)d_in[4];
    const float* W2 = (const float*)d_in[5];  const float* b2 = (const float*)d_in[6];
    const float* W3 = (const float*)d_in[7];  const float* b3 = (const float*)d_in[8];
    const float* Wa = (const float*)d_in[9];  const float* ba = (const float*)d_in[10];
    const float* Wo = (const float*)d_in[11]; const float* bo = (const float*)d_in[12];

    const int E = in_sizes[1] / 2;
    const int N = in_sizes[2];
    const int G = 64;
    const int NB = cdiv(N, 1 << BSH);     // 391
    const int NCH = cdiv(E, CH_E);        // 1563

    const int* srcp = edge;
    const int* dstp = edge + E;

    // Workspace
    char* base = (char*)d_ws;
    size_t off = 0;
    float* dinv   = (float*)(base + off); off = align256(off + sizeof(float) * N);
    unsigned short* lp16 = (unsigned short*)(base + off); off = align256(off + sizeof(short) * E);
    int* cnt_mat  = (int*)(base + off); off = align256(off + sizeof(int) * (size_t)NB * NCH);
    int* offs_mat = (int*)(base + off); off = align256(off + sizeof(int) * (size_t)NB * NCH);
    int* btot     = (int*)(base + off); off = align256(off + sizeof(int) * (NB + 1));
    int* bbase    = (int*)(base + off); off = align256(off + sizeof(int) * (NB + 1));
    unsigned int* bedges = (unsigned int*)(base + off); off = align256(off + sizeof(int) * E);
    int* rowptr   = (int*)(base + off); off = align256(off + sizeof(int) * (N + 1));
    int* csr_src  = (int*)(base + off); off = align256(off + sizeof(int) * E);
    unsigned short* Hb1 = (unsigned short*)(base + off); off = align256(off + sizeof(short) * (size_t)N * 16);
    unsigned short* Hb2 = (unsigned short*)(base + off); off = align256(off + sizeof(short) * (size_t)N * 16);
    float* P2     = (float*)(base + off); off = align256(off + sizeof(float) * (size_t)N * 16);
    unsigned short* Hb3 = (unsigned short*)(base + off); off = align256(off + sizeof(short) * (size_t)N * 32);
    unsigned short* Hb3a = (unsigned short*)(base + off); off = align256(off + sizeof(short) * (size_t)N * 16);
    unsigned short* Hb3b = (unsigned short*)(base + off); off = align256(off + sizeof(short) * (size_t)N * 16);
    float* h3     = (float*)(base + off); off = align256(off + sizeof(float) * (size_t)N * 32);
    float* sums   = (float*)(base + off); off = align256(off + sizeof(float) * G * 32);

    // ---- Atomic-free binning -> bucket-sorted bedges ----
    k_countA<<<NCH, THREADS, 0, stream>>>(dstp, lp16, cnt_mat, E, NB, NCH);
    k_sumK1<<<NB, THREADS, 0, stream>>>(cnt_mat, btot, NCH);
    k_scanK2<<<1, MAXNB, 0, stream>>>(btot, bbase, NB, E);
    k_scanK3<<<NB, THREADS, 0, stream>>>(cnt_mat, bbase, offs_mat, NCH);
    k_scatter2<<<NCH, THREADS, 0, stream>>>(srcp, dstp, lp16, offs_mat, bedges, E, NB, NCH);

    // ---- CSR (rowptr, csr_src, dinv) from bucket-sorted edges ----
    k_bucket_csr<<<NB, TCSR, 0, stream>>>(bedges, bbase, rowptr, dinv, csr_src, N);

    // ---- Layer 1: Hb1 = bf16((x@W1)*dinv); pull16 -> Hb2 = bf16(relu(.+b1)*dinv) ----
    k_gemm1<<<cdiv(N, THREADS), THREADS, 0, stream>>>(x, W1, dinv, Hb1, N);
    k_pull<1><<<cdiv(N, 128), THREADS, 0, stream>>>(rowptr, csr_src, dinv, Hb1, b1, Hb2, N);

    // ---- Layer 2 aggregate at input width: P2 = pull16(Hb2) ----
    k_pull<2><<<cdiv(N, 128), THREADS, 0, stream>>>(rowptr, csr_src, dinv, Hb2, b1 /*unused*/, P2, N);

    // ---- Fused node MLP (R9 form) + plane split ----
    k_mlp<<<cdiv(N, THREADS), THREADS, 0, stream>>>(P2, W2, b2, W3, dinv, Hb3, N);
    k_split<<<cdiv(N, THREADS), THREADS, 0, stream>>>(Hb3, Hb3a, Hb3b, N);

    // ---- Layer 3 aggregate: two plane pulls (each 3.2MB table, L2-resident) ----
    k_pull3p<<<cdiv(N, 128), THREADS, 0, stream>>>(rowptr, csr_src, dinv, Hb3a, b3, h3, N, 0);
    k_pull3p<<<cdiv(N, 128), THREADS, 0, stream>>>(rowptr, csr_src, dinv, Hb3b, b3, h3, N, 16);

    // ---- Pool (parallel, run-length atomics) + head ----
    k_zero_f<<<cdiv(G * 32, THREADS), THREADS, 0, stream>>>(sums, G * 32);
    k_pool_part<<<cdiv(N, POOL_C), THREADS, 0, stream>>>(h3, batch, sums, N);
    k_head<<<G, 64, 0, stream>>>(sums, batch, N, Wa, ba, Wo, bo, (float*)d_out);
}

// Round 13
// 394.093 us; speedup vs baseline: 1.2385x; 1.0369x over previous
//
#include <hip/hip_runtime.h>
#include <hip/hip_bf16.h>
#include <math.h>

// ActorGNN R13: R12 with k_mlp re-parallelized: 8 lanes/node, 32 nodes/block
// (grid 3125, ~24 waves/CU vs 1.5 waves/SIMD before). Everything else identical.
// N=100000, E=3200000, G=64.

#define THREADS 256
#define TCSR 512
#define BSH 8
#define MAXNB 512
#define CH_E 2048
#define CPT 8
#define POOL_C 512

// ---- bf16 helpers ----
__device__ inline unsigned short f2bf(float f) {
    unsigned int u = __float_as_uint(f);
    return (unsigned short)((u + 0x7fffu + ((u >> 16) & 1u)) >> 16);  // RNE
}
__device__ inline unsigned int pk2bf(float a, float b) {
    return (unsigned int)f2bf(a) | ((unsigned int)f2bf(b) << 16);
}
__device__ inline float bflo(unsigned int u) { return __uint_as_float(u << 16); }
__device__ inline float bfhi(unsigned int u) { return __uint_as_float(u & 0xffff0000u); }
__device__ inline void unpk8(const uint4 u, float* f) {
    f[0] = bflo(u.x); f[1] = bfhi(u.x); f[2] = bflo(u.y); f[3] = bfhi(u.y);
    f[4] = bflo(u.z); f[5] = bfhi(u.z); f[6] = bflo(u.w); f[7] = bfhi(u.w);
}

// ---- Atomic-free binning: pass A counts + records local position ----
__global__ void k_countA(const int* __restrict__ dst, unsigned short* __restrict__ lp16,
                         int* __restrict__ cnt_mat, int E, int NB, int NCH) {
    __shared__ int hist[MAXNB];
    int t = threadIdx.x, chunk = blockIdx.x;
    for (int h = t; h < NB; h += THREADS) hist[h] = 0;
    __syncthreads();
    int e0 = chunk * CH_E, e1 = min(E, e0 + CH_E);
    for (int e = e0 + t; e < e1; e += THREADS) {
        int h = dst[e] >> BSH;
        int lp = atomicAdd(&hist[h], 1);
        lp16[e] = (unsigned short)lp;
    }
    __syncthreads();
    for (int h = t; h < NB; h += THREADS) cnt_mat[(size_t)h * NCH + chunk] = hist[h];
}

// K1: bucket totals
__global__ void k_sumK1(const int* __restrict__ cnt_mat, int* __restrict__ bucket_tot, int NCH) {
    __shared__ int red[THREADS];
    int b = blockIdx.x, t = threadIdx.x;
    int s = 0;
    for (int c = t; c < NCH; c += THREADS) s += cnt_mat[(size_t)b * NCH + c];
    red[t] = s;
    __syncthreads();
    for (int off = THREADS / 2; off > 0; off >>= 1) {
        if (t < off) red[t] += red[t + off];
        __syncthreads();
    }
    if (t == 0) bucket_tot[b] = red[0];
}

// K2: single block exclusive scan of NB bucket totals -> bucket_base; [NB]=E
__global__ void k_scanK2(const int* __restrict__ bucket_tot, int* __restrict__ bucket_base,
                         int NB, int E) {
    __shared__ int sh[MAXNB];
    int t = threadIdx.x;  // 512
    int v = (t < NB) ? bucket_tot[t] : 0;
    sh[t] = v;
    __syncthreads();
    for (int off = 1; off < MAXNB; off <<= 1) {
        int u = (t >= off) ? sh[t - off] : 0;
        __syncthreads();
        sh[t] += u;
        __syncthreads();
    }
    if (t < NB) bucket_base[t] = sh[t] - v;
    if (t == 0) bucket_base[NB] = E;
}

// K3: per-bucket exclusive scan over chunks + bucket base -> offs_mat
__global__ void k_scanK3(const int* __restrict__ cnt_mat, const int* __restrict__ bucket_base,
                         int* __restrict__ offs_mat, int NCH) {
    __shared__ int sh[THREADS];
    int b = blockIdx.x, t = threadIdx.x;
    int c0 = t * CPT;
    int v[CPT];
    int s = 0;
#pragma unroll
    for (int k = 0; k < CPT; ++k) {
        int c = c0 + k;
        v[k] = (c < NCH) ? cnt_mat[(size_t)b * NCH + c] : 0;
        s += v[k];
    }
    sh[t] = s;
    __syncthreads();
    for (int off = 1; off < THREADS; off <<= 1) {
        int u = (t >= off) ? sh[t - off] : 0;
        __syncthreads();
        sh[t] += u;
        __syncthreads();
    }
    int run = bucket_base[b] + sh[t] - s;
#pragma unroll
    for (int k = 0; k < CPT; ++k) {
        int c = c0 + k;
        if (c < NCH) { offs_mat[(size_t)b * NCH + c] = run; run += v[k]; }
    }
}

// Pass B: deterministic scatter. pos = offs[bucket][chunk] + lp. No atomics.
__global__ void k_scatter2(const int* __restrict__ src, const int* __restrict__ dst,
                           const unsigned short* __restrict__ lp16,
                           const int* __restrict__ offs_mat,
                           unsigned int* __restrict__ bedges, int E, int NB, int NCH) {
    __shared__ int offs[MAXNB];
    int t = threadIdx.x, chunk = blockIdx.x;
    for (int h = t; h < NB; h += THREADS) offs[h] = offs_mat[(size_t)h * NCH + chunk];
    __syncthreads();
    int e0 = chunk * CH_E, e1 = min(E, e0 + CH_E);
    for (int e = e0 + t; e < e1; e += THREADS) {
        int d = dst[e];
        int h = d >> BSH;
        int pos = offs[h] + (int)lp16[e];
        bedges[pos] = ((unsigned int)src[e] << BSH) | (unsigned int)(d & ((1 << BSH) - 1));
    }
}

// Block = bucket (<=256 nodes), 512 threads: LDS histogram -> rowptr, dinv;
// place srcs into csr_src.
__global__ void k_bucket_csr(const unsigned int* __restrict__ bedges,
                             const int* __restrict__ bucket_base,
                             int* __restrict__ rowptr, float* __restrict__ dinv,
                             int* __restrict__ csr_src, int N) {
    __shared__ int hist[256];
    __shared__ int sc[256];
    __shared__ int cur[256];
    int t = threadIdx.x;   // 0..511
    int b = blockIdx.x;
    int base = bucket_base[b];
    int end = bucket_base[b + 1];
    if (t < 256) hist[t] = 0;
    __syncthreads();
    for (int i = base + t; i < end; i += TCSR)
        atomicAdd(&hist[bedges[i] & 255], 1);
    __syncthreads();
    int c = 0;
    if (t < 256) { c = hist[t]; sc[t] = c; }
    __syncthreads();
    for (int off = 1; off < 256; off <<= 1) {
        int u = (t >= off && t < 256) ? sc[t - off] : 0;
        __syncthreads();
        if (t < 256) sc[t] += u;
        __syncthreads();
    }
    if (t < 256) {
        int excl = sc[t] - c;
        int node = (b << BSH) + t;
        if (node < N) {
            rowptr[node] = base + excl;
            dinv[node] = (float)(1.0 / sqrt((double)(c + 1)));
        }
        cur[t] = excl;
    }
    __syncthreads();
    for (int i = base + t; i < end; i += TCSR) {
        unsigned int u = bedges[i];
        int ln = (int)(u & 255);
        int p = atomicAdd(&cur[ln], 1);
        csr_src[base + p] = (int)(u >> BSH);
    }
}

// Row-per-thread GEMM: Hb1[n] = bf16((x[n] @ W1) * dinv[n]); W1^T staged in LDS.
__global__ __launch_bounds__(256) void k_gemm1(const float* __restrict__ X,
                        const float* __restrict__ W,
                        const float* __restrict__ dinv, unsigned short* __restrict__ H, int N) {
    __shared__ float Wt[16 * 128];   // Wt[j][k] = W[k][j]
    int t = threadIdx.x;
    for (int i = t; i < 16 * 128; i += THREADS) {
        int j = i >> 7, k = i & 127;
        Wt[i] = W[k * 16 + j];
    }
    __syncthreads();
    int row = blockIdx.x * THREADS + t;
    if (row >= N) return;
    const float4* xr = (const float4*)(X + (size_t)row * 128);
    float acc[16];
#pragma unroll
    for (int j = 0; j < 16; ++j) acc[j] = 0.0f;
#pragma unroll 4
    for (int k4 = 0; k4 < 32; ++k4) {
        float4 xv = xr[k4];
#pragma unroll
        for (int j = 0; j < 16; ++j) {
            const float4 wv = *(const float4*)&Wt[j * 128 + k4 * 4];  // uniform -> broadcast
            acc[j] += xv.x * wv.x + xv.y * wv.y + xv.z * wv.z + xv.w * wv.w;
        }
    }
    float di = dinv[row];
    uint4 oa, ob;
    oa.x = pk2bf(acc[0] * di, acc[1] * di);
    oa.y = pk2bf(acc[2] * di, acc[3] * di);
    oa.z = pk2bf(acc[4] * di, acc[5] * di);
    oa.w = pk2bf(acc[6] * di, acc[7] * di);
    ob.x = pk2bf(acc[8] * di, acc[9] * di);
    ob.y = pk2bf(acc[10] * di, acc[11] * di);
    ob.z = pk2bf(acc[12] * di, acc[13] * di);
    ob.w = pk2bf(acc[14] * di, acc[15] * di);
    uint4* outr = (uint4*)(H + (size_t)row * 16);
    outr[0] = oa;
    outr[1] = ob;
}

// Pull from bf16 table (F=16): 8 features/lane, pipelined index prefetch.
// MODE 1: bf16 out = relu(t+b)*dinv   MODE 2: fp32 out = t
template<int MODE>
__global__ void k_pull(const int* __restrict__ rowptr, const int* __restrict__ csr_src,
                       const float* __restrict__ dinv, const unsigned short* __restrict__ Hb,
                       const float* __restrict__ bias, void* __restrict__ outp, int N) {
    const int F = 16;
    int node = blockIdx.x * 128 + (threadIdx.x >> 1);
    int fo = (threadIdx.x & 1) * 8;
    if (node >= N) return;
    int beg = rowptr[node], end = rowptr[node + 1];
    float acc[8] = {0.f, 0.f, 0.f, 0.f, 0.f, 0.f, 0.f, 0.f};
    int i = beg;
    int s0, s1, s2, s3;
    if (i + 4 <= end) { s0 = csr_src[i]; s1 = csr_src[i + 1]; s2 = csr_src[i + 2]; s3 = csr_src[i + 3]; }
    for (; i + 8 <= end; i += 4) {
        int n0 = csr_src[i + 4], n1 = csr_src[i + 5], n2 = csr_src[i + 6], n3 = csr_src[i + 7];
        uint4 g0 = *(const uint4*)(Hb + (size_t)s0 * F + fo);
        uint4 g1 = *(const uint4*)(Hb + (size_t)s1 * F + fo);
        uint4 g2 = *(const uint4*)(Hb + (size_t)s2 * F + fo);
        uint4 g3 = *(const uint4*)(Hb + (size_t)s3 * F + fo);
        float f0[8], f1[8], f2[8], f3[8];
        unpk8(g0, f0); unpk8(g1, f1); unpk8(g2, f2); unpk8(g3, f3);
#pragma unroll
        for (int j = 0; j < 8; ++j) acc[j] += (f0[j] + f1[j]) + (f2[j] + f3[j]);
        s0 = n0; s1 = n1; s2 = n2; s3 = n3;
    }
    if (i + 4 <= end) {
        uint4 g0 = *(const uint4*)(Hb + (size_t)s0 * F + fo);
        uint4 g1 = *(const uint4*)(Hb + (size_t)s1 * F + fo);
        uint4 g2 = *(const uint4*)(Hb + (size_t)s2 * F + fo);
        uint4 g3 = *(const uint4*)(Hb + (size_t)s3 * F + fo);
        float f0[8], f1[8], f2[8], f3[8];
        unpk8(g0, f0); unpk8(g1, f1); unpk8(g2, f2); unpk8(g3, f3);
#pragma unroll
        for (int j = 0; j < 8; ++j) acc[j] += (f0[j] + f1[j]) + (f2[j] + f3[j]);
        i += 4;
    }
    for (; i < end; ++i) {
        int s = csr_src[i];
        uint4 g = *(const uint4*)(Hb + (size_t)s * F + fo);
        float f[8];
        unpk8(g, f);
#pragma unroll
        for (int j = 0; j < 8; ++j) acc[j] += f[j];
    }
    uint4 gs = *(const uint4*)(Hb + (size_t)node * F + fo);
    float sf[8];
    unpk8(gs, sf);
    float di = dinv[node];
    float tv[8];
#pragma unroll
    for (int j = 0; j < 8; ++j) tv[j] = di * (acc[j] + sf[j]);
    if (MODE == 1) {
        float w[8];
#pragma unroll
        for (int j = 0; j < 8; ++j) w[j] = fmaxf(tv[j] + bias[fo + j], 0.0f) * di;
        uint4 st;
        st.x = pk2bf(w[0], w[1]); st.y = pk2bf(w[2], w[3]);
        st.z = pk2bf(w[4], w[5]); st.w = pk2bf(w[6], w[7]);
        *(uint4*)((unsigned short*)outp + (size_t)node * F + fo) = st;
    } else {
        float* of = (float*)outp + (size_t)node * F + fo;
        float4 o0, o1;
        o0.x = tv[0]; o0.y = tv[1]; o0.z = tv[2]; o0.w = tv[3];
        o1.x = tv[4]; o1.y = tv[5]; o1.z = tv[6]; o1.w = tv[7];
        ((float4*)of)[0] = o0; ((float4*)of)[1] = o1;
    }
}

// Layer-3 plane pull: gather from one N×16 bf16 plane (3.2MB, L2-resident),
// write fp32 into h3 rows (stride 32) at offset fofs. Pipelined prefetch.
__global__ void k_pull3p(const int* __restrict__ rowptr, const int* __restrict__ csr_src,
                         const float* __restrict__ dinv, const unsigned short* __restrict__ plane,
                         const float* __restrict__ bias, float* __restrict__ h3,
                         int N, int fofs) {
    int node = blockIdx.x * 128 + (threadIdx.x >> 1);
    int fo = (threadIdx.x & 1) * 8;
    if (node >= N) return;
    int beg = rowptr[node], end = rowptr[node + 1];
    float acc[8] = {0.f, 0.f, 0.f, 0.f, 0.f, 0.f, 0.f, 0.f};
    int i = beg;
    int s0, s1, s2, s3;
    if (i + 4 <= end) { s0 = csr_src[i]; s1 = csr_src[i + 1]; s2 = csr_src[i + 2]; s3 = csr_src[i + 3]; }
    for (; i + 8 <= end; i += 4) {
        int n0 = csr_src[i + 4], n1 = csr_src[i + 5], n2 = csr_src[i + 6], n3 = csr_src[i + 7];
        uint4 g0 = *(const uint4*)(plane + (size_t)s0 * 16 + fo);
        uint4 g1 = *(const uint4*)(plane + (size_t)s1 * 16 + fo);
        uint4 g2 = *(const uint4*)(plane + (size_t)s2 * 16 + fo);
        uint4 g3 = *(const uint4*)(plane + (size_t)s3 * 16 + fo);
        float f0[8], f1[8], f2[8], f3[8];
        unpk8(g0, f0); unpk8(g1, f1); unpk8(g2, f2); unpk8(g3, f3);
#pragma unroll
        for (int j = 0; j < 8; ++j) acc[j] += (f0[j] + f1[j]) + (f2[j] + f3[j]);
        s0 = n0; s1 = n1; s2 = n2; s3 = n3;
    }
    if (i + 4 <= end) {
        uint4 g0 = *(const uint4*)(plane + (size_t)s0 * 16 + fo);
        uint4 g1 = *(const uint4*)(plane + (size_t)s1 * 16 + fo);
        uint4 g2 = *(const uint4*)(plane + (size_t)s2 * 16 + fo);
        uint4 g3 = *(const uint4*)(plane + (size_t)s3 * 16 + fo);
        float f0[8], f1[8], f2[8], f3[8];
        unpk8(g0, f0); unpk8(g1, f1); unpk8(g2, f2); unpk8(g3, f3);
#pragma unroll
        for (int j = 0; j < 8; ++j) acc[j] += (f0[j] + f1[j]) + (f2[j] + f3[j]);
        i += 4;
    }
    for (; i < end; ++i) {
        int s = csr_src[i];
        uint4 g = *(const uint4*)(plane + (size_t)s * 16 + fo);
        float f[8];
        unpk8(g, f);
#pragma unroll
        for (int j = 0; j < 8; ++j) acc[j] += f[j];
    }
    uint4 gs = *(const uint4*)(plane + (size_t)node * 16 + fo);
    float sf[8];
    unpk8(gs, sf);
    float di = dinv[node];
    int fb = fofs + fo;
    float4 o0, o1;
    o0.x = di * (acc[0] + sf[0]) + bias[fb + 0];
    o0.y = di * (acc[1] + sf[1]) + bias[fb + 1];
    o0.z = di * (acc[2] + sf[2]) + bias[fb + 2];
    o0.w = di * (acc[3] + sf[3]) + bias[fb + 3];
    o1.x = di * (acc[4] + sf[4]) + bias[fb + 4];
    o1.y = di * (acc[5] + sf[5]) + bias[fb + 5];
    o1.z = di * (acc[6] + sf[6]) + bias[fb + 6];
    o1.w = di * (acc[7] + sf[7]) + bias[fb + 7];
    float* of = h3 + (size_t)node * 32 + fb;
    ((float4*)of)[0] = o0;
    ((float4*)of)[1] = o1;
}

// Re-parallelized MLP: 8 lanes/node, 32 nodes/block (grid ~3125).
// Phase A: lane l computes hidden j = jj*8+l (consecutive across lanes).
// Phase B: lane l computes outputs m = l*4..l*4+3 (contiguous 8B store).
__global__ __launch_bounds__(256) void k_mlp(const float* __restrict__ P2,
                      const float* __restrict__ W2, const float* __restrict__ b2,
                      const float* __restrict__ W3, const float* __restrict__ dinv,
                      unsigned short* __restrict__ Hb3, int N) {
    __shared__ float W2t[64 * 16];   // W2t[j][k] = W2[k][j]
    __shared__ float W3t[32 * 68];   // W3t[m][j] = W3[j][m], row pad 68
    __shared__ float b2s[64];
    __shared__ float pS[32 * 16];    // per-node inputs
    __shared__ float aS[32 * 68];    // per-node hidden, row pad 68
    int t = threadIdx.x;
    for (int i = t; i < 64 * 16; i += THREADS) {
        int j = i >> 4, k = i & 15;
        W2t[i] = W2[k * 64 + j];
    }
    for (int i = t; i < 32 * 64; i += THREADS) {
        int m = i & 31, j = i >> 5;
        W3t[m * 68 + j] = W3[j * 32 + m];
    }
    if (t < 64) b2s[t] = b2[t];
    int s = t >> 3;          // node slot 0..31
    int l = t & 7;           // lane-in-node 0..7
    int n = blockIdx.x * 32 + s;
    bool valid = (n < N);
    __syncthreads();
    // stage P2 row: lanes 0..3 load float4 each
    if (valid && l < 4)
        *(float4*)&pS[s * 16 + l * 4] = ((const float4*)(P2 + (size_t)n * 16))[l];
    __syncthreads();
    if (valid) {
        float4 pa = *(const float4*)&pS[s * 16 + 0];
        float4 pb = *(const float4*)&pS[s * 16 + 4];
        float4 pc = *(const float4*)&pS[s * 16 + 8];
        float4 pd = *(const float4*)&pS[s * 16 + 12];
#pragma unroll
        for (int jj = 0; jj < 8; ++jj) {
            int j = jj * 8 + l;
            const float4* w = (const float4*)&W2t[j * 16];
            float4 w0 = w[0], w1 = w[1], w2q = w[2], w3q = w[3];
            float acc = b2s[j];
            acc += pa.x * w0.x + pa.y * w0.y + pa.z * w0.z + pa.w * w0.w;
            acc += pb.x * w1.x + pb.y * w1.y + pb.z * w1.z + pb.w * w1.w;
            acc += pc.x * w2q.x + pc.y * w2q.y + pc.z * w2q.z + pc.w * w2q.w;
            acc += pd.x * w3q.x + pd.y * w3q.y + pd.z * w3q.z + pd.w * w3q.w;
            aS[s * 68 + j] = fmaxf(acc, 0.0f);
        }
    }
    __syncthreads();
    if (valid) {
        float o0 = 0.f, o1 = 0.f, o2 = 0.f, o3 = 0.f;
        int m0 = l * 4;
#pragma unroll
        for (int k4 = 0; k4 < 16; ++k4) {
            float4 av = *(const float4*)&aS[s * 68 + k4 * 4];
            float4 wv0 = *(const float4*)&W3t[(m0 + 0) * 68 + k4 * 4];
            float4 wv1 = *(const float4*)&W3t[(m0 + 1) * 68 + k4 * 4];
            float4 wv2 = *(const float4*)&W3t[(m0 + 2) * 68 + k4 * 4];
            float4 wv3 = *(const float4*)&W3t[(m0 + 3) * 68 + k4 * 4];
            o0 += av.x * wv0.x + av.y * wv0.y + av.z * wv0.z + av.w * wv0.w;
            o1 += av.x * wv1.x + av.y * wv1.y + av.z * wv1.z + av.w * wv1.w;
            o2 += av.x * wv2.x + av.y * wv2.y + av.z * wv2.z + av.w * wv2.w;
            o3 += av.x * wv3.x + av.y * wv3.y + av.z * wv3.z + av.w * wv3.w;
        }
        float di = dinv[n];
        uint2 st;
        st.x = pk2bf(o0 * di, o1 * di);
        st.y = pk2bf(o2 * di, o3 * di);
        *(uint2*)(Hb3 + (size_t)n * 32 + m0) = st;
    }
}

// Split N×32 table into two N×16 planes (bandwidth-trivial).
__global__ void k_split(const unsigned short* __restrict__ Hb3,
                        unsigned short* __restrict__ A, unsigned short* __restrict__ B, int N) {
    int n = blockIdx.x * blockDim.x + threadIdx.x;
    if (n >= N) return;
    const uint4* r = (const uint4*)(Hb3 + (size_t)n * 32);
    uint4 q0 = r[0], q1 = r[1], q2 = r[2], q3 = r[3];
    uint4* pa = (uint4*)(A + (size_t)n * 16);
    uint4* pb = (uint4*)(B + (size_t)n * 16);
    pa[0] = q0; pa[1] = q1;
    pb[0] = q2; pb[1] = q3;
}

__global__ void k_zero_f(float* p, int n) {
    int i = blockIdx.x * blockDim.x + threadIdx.x;
    if (i < n) p[i] = 0.0f;
}

// Parallel segmented pooling: run-length accumulate, atomic on graph boundary.
__global__ void k_pool_part(const float* __restrict__ h3, const int* __restrict__ batch,
                            float* __restrict__ sums, int N) {
    int f = threadIdx.x & 31;
    int sub = threadIdx.x >> 5;   // 8 node-lanes
    int n0 = blockIdx.x * POOL_C;
    int n1 = min(N, n0 + POOL_C);
    float acc = 0.0f;
    int curg = -1;
    for (int n = n0 + sub; n < n1; n += 8) {
        int g = batch[n];
        if (g != curg) {
            if (curg >= 0) atomicAdd(&sums[curg * 32 + f], acc);
            acc = 0.0f;
            curg = g;
        }
        acc += h3[(size_t)n * 32 + f];
    }
    if (curg >= 0) atomicAdd(&sums[curg * 32 + f], acc);
}

// Head: cnt via binary search; a=relu(pooled@Wa+ba); out=tanh(a@Wo+bo)
__global__ void k_head(const float* __restrict__ sums, const int* __restrict__ batch, int N,
                       const float* __restrict__ Wa, const float* __restrict__ ba,
                       const float* __restrict__ Wo, const float* __restrict__ bo,
                       float* __restrict__ out) {
    int g = blockIdx.x;
    int j = threadIdx.x;  // 64 threads
    int lo = 0, hi = N;
    while (lo < hi) { int m = (lo + hi) >> 1; if (batch[m] < g) lo = m + 1; else hi = m; }
    int start = lo;
    lo = start; hi = N;
    while (lo < hi) { int m = (lo + hi) >> 1; if (batch[m] < g + 1) lo = m + 1; else hi = m; }
    int cnt = lo - start;
    float inv = 1.0f / (float)(cnt > 0 ? cnt : 1);

    __shared__ float p[32];
    __shared__ float a[64];
    if (j < 32) p[j] = sums[g * 32 + j] * inv;
    __syncthreads();
    float acc = ba[j];
#pragma unroll
    for (int k = 0; k < 32; ++k) acc += p[k] * Wa[k * 64 + j];
    a[j] = fmaxf(acc, 0.0f);
    __syncthreads();
    if (j < 32) {
        float acc2 = bo[j];
#pragma unroll
        for (int k = 0; k < 64; ++k) acc2 += a[k] * Wo[k * 32 + j];
        out[g * 32 + j] = tanhf(acc2);
    }
}

static inline int cdiv(long long a, int b) { return (int)((a + b - 1) / b); }
static inline size_t align256(size_t x) { return (x + 255) & ~(size_t)255; }

extern "C" void kernel_launch(void* const* d_in, const int* in_sizes, int n_in,
                              void* d_out, int out_size, void* d_ws, size_t ws_size,
                              hipStream_t stream) {
    const float* x     = (const float*)d_in[0];
    const int*   edge  = (const int*)d_in[1];
    const int*   batch = (const int*)d_in[2];
    const float* W1 = (const float*)d_in[3];  const float* b1 = (const float*)d_in[4];
    const float* W2 = (const float*)d_in[5];  const float* b2 = (const float*)d_in[6];
    const float* W3 = (const float*)d_in[7];  const float* b3 = (const float*)d_in[8];
    const float* Wa = (const float*)d_in[9];  const float* ba = (const float*)d_in[10];
    const float* Wo = (const float*)d_in[11]; const float* bo = (const float*)d_in[12];

    const int E = in_sizes[1] / 2;
    const int N = in_sizes[2];
    const int G = 64;
    const int NB = cdiv(N, 1 << BSH);     // 391
    const int NCH = cdiv(E, CH_E);        // 1563

    const int* srcp = edge;
    const int* dstp = edge + E;

    // Workspace
    char* base = (char*)d_ws;
    size_t off = 0;
    float* dinv   = (float*)(base + off); off = align256(off + sizeof(float) * N);
    unsigned short* lp16 = (unsigned short*)(base + off); off = align256(off + sizeof(short) * E);
    int* cnt_mat  = (int*)(base + off); off = align256(off + sizeof(int) * (size_t)NB * NCH);
    int* offs_mat = (int*)(base + off); off = align256(off + sizeof(int) * (size_t)NB * NCH);
    int* btot     = (int*)(base + off); off = align256(off + sizeof(int) * (NB + 1));
    int* bbase    = (int*)(base + off); off = align256(off + sizeof(int) * (NB + 1));
    unsigned int* bedges = (unsigned int*)(base + off); off = align256(off + sizeof(int) * E);
    int* rowptr   = (int*)(base + off); off = align256(off + sizeof(int) * (N + 1));
    int* csr_src  = (int*)(base + off); off = align256(off + sizeof(int) * E);
    unsigned short* Hb1 = (unsigned short*)(base + off); off = align256(off + sizeof(short) * (size_t)N * 16);
    unsigned short* Hb2 = (unsigned short*)(base + off); off = align256(off + sizeof(short) * (size_t)N * 16);
    float* P2     = (float*)(base + off); off = align256(off + sizeof(float) * (size_t)N * 16);
    unsigned short* Hb3 = (unsigned short*)(base + off); off = align256(off + sizeof(short) * (size_t)N * 32);
    unsigned short* Hb3a = (unsigned short*)(base + off); off = align256(off + sizeof(short) * (size_t)N * 16);
    unsigned short* Hb3b = (unsigned short*)(base + off); off = align256(off + sizeof(short) * (size_t)N * 16);
    float* h3     = (float*)(base + off); off = align256(off + sizeof(float) * (size_t)N * 32);
    float* sums   = (float*)(base + off); off = align256(off + sizeof(float) * G * 32);

    // ---- Atomic-free binning -> bucket-sorted bedges ----
    k_countA<<<NCH, THREADS, 0, stream>>>(dstp, lp16, cnt_mat, E, NB, NCH);
    k_sumK1<<<NB, THREADS, 0, stream>>>(cnt_mat, btot, NCH);
    k_scanK2<<<1, MAXNB, 0, stream>>>(btot, bbase, NB, E);
    k_scanK3<<<NB, THREADS, 0, stream>>>(cnt_mat, bbase, offs_mat, NCH);
    k_scatter2<<<NCH, THREADS, 0, stream>>>(srcp, dstp, lp16, offs_mat, bedges, E, NB, NCH);

    // ---- CSR (rowptr, csr_src, dinv) from bucket-sorted edges ----
    k_bucket_csr<<<NB, TCSR, 0, stream>>>(bedges, bbase, rowptr, dinv, csr_src, N);

    // ---- Layer 1: Hb1 = bf16((x@W1)*dinv); pull16 -> Hb2 = bf16(relu(.+b1)*dinv) ----
    k_gemm1<<<cdiv(N, THREADS), THREADS, 0, stream>>>(x, W1, dinv, Hb1, N);
    k_pull<1><<<cdiv(N, 128), THREADS, 0, stream>>>(rowptr, csr_src, dinv, Hb1, b1, Hb2, N);

    // ---- Layer 2 aggregate at input width: P2 = pull16(Hb2) ----
    k_pull<2><<<cdiv(N, 128), THREADS, 0, stream>>>(rowptr, csr_src, dinv, Hb2, b1 /*unused*/, P2, N);

    // ---- Fused node MLP (8 lanes/node) + plane split ----
    k_mlp<<<cdiv(N, 32), THREADS, 0, stream>>>(P2, W2, b2, W3, dinv, Hb3, N);
    k_split<<<cdiv(N, THREADS), THREADS, 0, stream>>>(Hb3, Hb3a, Hb3b, N);

    // ---- Layer 3 aggregate: two plane pulls (each 3.2MB table, L2-resident) ----
    k_pull3p<<<cdiv(N, 128), THREADS, 0, stream>>>(rowptr, csr_src, dinv, Hb3a, b3, h3, N, 0);
    k_pull3p<<<cdiv(N, 128), THREADS, 0, stream>>>(rowptr, csr_src, dinv, Hb3b, b3, h3, N, 16);

    // ---- Pool (parallel, run-length atomics) + head ----
    k_zero_f<<<cdiv(G * 32, THREADS), THREADS, 0, stream>>>(sums, G * 32);
    k_pool_part<<<cdiv(N, POOL_C), THREADS, 0, stream>>>(h3, batch, sums, N);
    k_head<<<G, 64, 0, stream>>>(sums, batch, N, Wa, ba, Wo, bo, (float*)d_out);
}